// Round 9
// baseline (222.841 us; speedup 1.0000x reference)
//
#include <hip/hip_runtime.h>

#define TWO_PI_F 6.283185307179586f
#define EPS_F 1e-6f
#define LOG2E_F 1.4426950408889634f
#define BATCH 32
#define GRIDB 256   // == CU count; 1 block/CU -> all blocks co-resident

// Replace non-finite by 0 (bit test so fast-math can't fold it away).
__device__ __forceinline__ float sane(float x) {
    return ((__float_as_uint(x) & 0x7f800000u) == 0x7f800000u) ? 0.f : x;
}

// Software grid barrier (one-shot per index, counters memset to 0 on-stream
// before each launch). Device-scope atomics + __threadfence (L2 writeback on
// CDNA) per G16. Bounded spin: degrades instead of hanging if assumptions break.
__device__ __forceinline__ void grid_barrier(unsigned int* cnt, int idx) {
    __syncthreads();   // each wave drains its own vmcnt at the barrier
    if (threadIdx.x == 0) {
        __threadfence();                       // publish this block's writes
        atomicAdd(&cnt[idx * 32], 1u);         // device-scope by default
        long long guard = 0;
        while (__hip_atomic_load(&cnt[idx * 32], __ATOMIC_RELAXED,
                                 __HIP_MEMORY_SCOPE_AGENT) < GRIDB
               && guard < (1LL << 26)) {
            __builtin_amdgcn_s_sleep(2);
            ++guard;
        }
        __threadfence();                       // acquire others' writes
    }
    __syncthreads();
}

// Per-layer shared-memory layout. Staging arrays (dead after conv) union'd
// with the eval/rank partial buffer.
template<int LI, int ND, int NK, int NCOMP, int KP, int TPG, int G>
struct LayerSmem {
    struct StageT {
        float4 d_c[LI*ND];
        float4 k_c[LI*NK];
        float  d_w[LI*ND], d_px[LI*ND], d_py[LI*ND];
        float  k_w[LI*NK], k_px[LI*NK], k_py[LI*NK];
    };
    static constexpr int NCOMP4 = (NCOMP + 3) & ~3;
    static constexpr int ACCN   = (G > 1) ? (G - 1) * TPG * KP : 1;
    float2 cPos[NCOMP];   // px, py
    float4 nP[NCOMP];     // a, b, c, d   (log2e-folded quadform poly)
    float4 nQ[NCOMP];     // e, f, w, 0
    float4 cC[NCOMP];     // C00,C01,C10,C11
    float  w2s[NCOMP];
    alignas(16) float a2s[NCOMP4];
    union { StageT st; float accbuf[ACCN]; } u;
    float scr[64];
    float selint[32];
    float dscale[LI];
};

struct FinalSmem { float scale3[10]; float integ[10]; float red2[2]; };

// One fused layer phase: [prev batchnorm] -> gm_convolve -> eval_at_centers
// (polynomial form, LDS-pipe uniform broadcasts) -> relu_fit (stable-rank
// top-KOUT) -> selected comps + per-(b,lo) abs-integral. blockDim == TPG*G.
template<int LO, int LI, int ND, int NK, int NCOMP, int KOUT,
         int KP, int TPG, int G, bool FIRST>
__device__ void layer_body(void* smem_raw, int blk,
    const float* __restrict__ in_x,            // FIRST: (B,1,64,7)
    const float* __restrict__ prev_sel,        // !FIRST: (B,LI,ND,7)
    const float* __restrict__ prev_tot,        // !FIRST: (B,LI)
    const float* __restrict__ kern,            // (LO,LI,NK,7)
    const float* __restrict__ bias,            // (LO,)
    float* __restrict__ out_sel,               // (B,LO,KOUT,7)
    float* __restrict__ out_tot)               // (B,LO)
{
    using SM = LayerSmem<LI, ND, NK, NCOMP, KP, TPG, G>;
    SM& sm = *reinterpret_cast<SM*>(smem_raw);
    constexpr int KUSE = NCOMP / KP;
    static_assert(KUSE * KP == NCOMP, "exact k tiling required");
    constexpr int CHUNK  = (NCOMP + G - 1) / G;
    constexpr int NCOMP4 = SM::NCOMP4;
    constexpr int NQn    = NCOMP4 / 4;
    constexpr int CQ     = (NQn + G - 1) / G;

    const int b   = blk / LO;
    const int lo  = blk % LO;
    const int tid = threadIdx.x;
    const int g   = tid / TPG;
    const int kt  = tid % TPG;
    const bool active = (kt < KUSE);

    // ---- Phase pre: incoming batchnorm + stage data/kernel into LDS
    if constexpr (FIRST) {
        if (tid < ND) {
            const float* s = in_x + (size_t)(b*ND + tid)*7;
            const float w  = sane(s[0]);
            const float c0 = sane(s[3]), c1 = sane(s[4]), c2 = sane(s[5]), c3 = sane(s[6]);
            sm.u.st.d_w[tid] = w; sm.u.st.d_px[tid] = sane(s[1]); sm.u.st.d_py[tid] = sane(s[2]);
            sm.u.st.d_c[tid] = make_float4(c0, c1, c2, c3);
            const float det = c0*c3 - c1*c2;
            sm.scr[tid] = sane(fabsf(w) * TWO_PI_F * sqrtf(fmaxf(det, EPS_F)));
        }
        __syncthreads();
        if (tid == 0) {
            float s = 0.f;
            for (int i = 0; i < ND; ++i) s += sm.scr[i];
            sm.dscale[0] = 1.f / (s + EPS_F);
        }
        __syncthreads();
        if (tid < ND) sm.u.st.d_w[tid] = sane(sm.u.st.d_w[tid] * sm.dscale[0]);
    } else {
        if (tid < LI) {
            float s = 0.f;
            for (int bb = 0; bb < BATCH; ++bb) s += prev_tot[bb*LI + tid];
            sm.dscale[tid] = 1.f / (s / (float)BATCH + EPS_F);
        }
        __syncthreads();
        if (tid < LI*ND) {
            const int li = tid / ND;
            const float* s = prev_sel + (size_t)(b*LI*ND + tid)*7;
            sm.u.st.d_w[tid]  = sane(s[0] * sm.dscale[li]);
            sm.u.st.d_px[tid] = s[1]; sm.u.st.d_py[tid] = s[2];
            sm.u.st.d_c[tid]  = make_float4(s[3], s[4], s[5], s[6]);
        }
    }
    if (tid < LI*NK) {
        const float* s = kern + (size_t)(lo*LI*NK + tid)*7;
        sm.u.st.k_w[tid]  = sane(s[0]);
        sm.u.st.k_px[tid] = sane(s[1]); sm.u.st.k_py[tid] = sane(s[2]);
        sm.u.st.k_c[tid]  = make_float4(sane(s[3]), sane(s[4]), sane(s[5]), sane(s[6]));
    }
    __syncthreads();

    // ---- Phase A: gm_convolve -> poly coefficients in LDS.
    // Flattening matches reference reshape: (li, nd, nk), nk fastest.
    if (tid < NCOMP) {
        const int li = tid / (ND*NK);
        const int r  = tid % (ND*NK);
        const int nd = r / NK, nk = r % NK;
        const int di = li*ND + nd, ki = li*NK + nk;
        const float4 dc = sm.u.st.d_c[di], kc = sm.u.st.k_c[ki];
        const float c0 = dc.x + kc.x, c1 = dc.y + kc.y, c2 = dc.z + kc.z, c3 = dc.w + kc.w;
        const float dd = dc.x*dc.w - dc.y*dc.z;
        const float dk = kc.x*kc.w - kc.y*kc.z;
        const float ds = c0*c3 - c1*c2;
        const float w  = sane(sm.u.st.d_w[di]*sm.u.st.k_w[ki]*TWO_PI_F
                              *sqrtf(fmaxf(dd*dk, 0.f) / fmaxf(ds, EPS_F)));
        const float px = sane(sm.u.st.d_px[di] + sm.u.st.k_px[ki]);
        const float py = sane(sm.u.st.d_py[di] + sm.u.st.k_py[ki]);
        const float inv = -0.5f * LOG2E_F / ds;      // fold -1/2 and log2e
        const float a   = sane(c3*inv);
        const float bb  = sane(-(c1 + c2)*inv);
        const float cc  = sane(c0*inv);
        const float dd2 = sane(-(2.f*a*px + bb*py));
        const float ee  = sane(-(2.f*cc*py + bb*px));
        const float ff  = sane((a*px + bb*py)*px + cc*py*py);
        sm.cPos[tid] = make_float2(px, py);
        sm.nP[tid]   = make_float4(a, bb, cc, dd2);
        sm.nQ[tid]   = make_float4(ee, ff, w, 0.f);
        sm.cC[tid]   = make_float4(sane(c0), sane(c1), sane(c2), sane(c3));
    }
    __syncthreads();

    // ---- Phase B: eval_at_centers, KP k-slots per thread, n split across G
    float kx[KP], ky[KP], kx2[KP], ky2[KP], kxy[KP], acc[KP];
    #pragma unroll
    for (int j = 0; j < KP; ++j) {
        acc[j] = 0.f; kx[j] = 0.f; ky[j] = 0.f;
        if (active) { const float2 p = sm.cPos[kt + j*KUSE]; kx[j] = p.x; ky[j] = p.y; }
        kx2[j] = kx[j]*kx[j]; ky2[j] = ky[j]*ky[j]; kxy[j] = kx[j]*ky[j];
    }
    {
        const int n0 = g*CHUNK;
        const int n1 = (n0 + CHUNK < NCOMP) ? (n0 + CHUNK) : NCOMP;
        #pragma unroll 2
        for (int n = n0; n < n1; ++n) {
            const float4 P = sm.nP[n];   // uniform-address broadcast (LDS pipe)
            const float4 Q = sm.nQ[n];
            #pragma unroll
            for (int j = 0; j < KP; ++j) {
                const float md = fmaf(P.x, kx2[j],
                                 fmaf(P.y, kxy[j],
                                 fmaf(P.z, ky2[j],
                                 fmaf(P.w, kx[j],
                                 fmaf(Q.x, ky[j], Q.y)))));
                acc[j] = fmaf(Q.z, exp2f(md), acc[j]);
            }
        }
    }
    if (g > 0 && active) {
        #pragma unroll
        for (int j = 0; j < KP; ++j) sm.u.accbuf[((g-1)*TPG + kt)*KP + j] = acc[j];
    }
    __syncthreads();

    const float bi = bias[lo];
    if (g == 0 && active) {
        #pragma unroll
        for (int j = 0; j < KP; ++j) {
            float s = acc[j];
            for (int gg = 1; gg < G; ++gg) s += sm.u.accbuf[((gg-1)*TPG + kt)*KP + j];
            const float v  = s + bi;
            const float sc = fmaxf(v, 0.f) / (fabsf(v) + EPS_F);
            const int   k  = kt + j*KUSE;
            const float ww = sane(sm.nQ[k].z * sc);
            sm.w2s[k] = ww;
            sm.a2s[k] = fabsf(ww);
        }
    }
    if constexpr (NCOMP4 > NCOMP) {
        if (tid >= NCOMP && tid < NCOMP4) sm.a2s[tid] = -1.f;  // pad: never ranks
    }
    __syncthreads();

    // ---- Phase C: stable-descending rank (== jax.lax.top_k order), group-split
    // rank(k) = #{j : a2s[j] > a2s[k]  or  (a2s[j] == a2s[k] and j < k)}
    int rank[KP];
    float myv[KP];
    #pragma unroll
    for (int j = 0; j < KP; ++j) rank[j] = 0;
    if (active) {
        #pragma unroll
        for (int j = 0; j < KP; ++j) myv[j] = sm.a2s[kt + j*KUSE];
        const int q0 = g*CQ;
        const int q1 = (q0 + CQ < NQn) ? (q0 + CQ) : NQn;
        for (int q = q0; q < q1; ++q) {
            const float4 v4 = ((const float4*)sm.a2s)[q];  // broadcast
            #pragma unroll
            for (int c = 0; c < 4; ++c) {
                const float vj = (c == 0) ? v4.x : (c == 1) ? v4.y : (c == 2) ? v4.z : v4.w;
                const int   jj = 4*q + c;
                #pragma unroll
                for (int j = 0; j < KP; ++j) {
                    const int myk = kt + j*KUSE;
                    rank[j] += (vj > myv[j] || (vj == myv[j] && jj < myk)) ? 1 : 0;
                }
            }
        }
        if (g > 0) {
            #pragma unroll
            for (int j = 0; j < KP; ++j) sm.u.accbuf[((g-1)*TPG + kt)*KP + j] = (float)rank[j];
        }
    }
    __syncthreads();

    // ---- Phase D: g==0 finalizes ranks, writes selected comps + integrals
    if (g == 0 && active) {
        #pragma unroll
        for (int j = 0; j < KP; ++j) {
            int r = rank[j];
            for (int gg = 1; gg < G; ++gg) r += (int)sm.u.accbuf[((gg-1)*TPG + kt)*KP + j];
            if (r < KOUT) {
                const int k = kt + j*KUSE;
                const float2 p = sm.cPos[k];
                const float4 c = sm.cC[k];
                const float ww = sm.w2s[k];
                float* dst = out_sel + (size_t)((b*LO + lo)*KOUT + r)*7;
                dst[0] = ww; dst[1] = p.x; dst[2] = p.y;
                dst[3] = c.x; dst[4] = c.y; dst[5] = c.z; dst[6] = c.w;
                const float det = c.x*c.w - c.y*c.z;
                sm.selint[r] = sane(fabsf(ww) * TWO_PI_F * sqrtf(fmaxf(det, EPS_F)));
            }
        }
    }
    __syncthreads();
    if (tid == 0) {
        float s = 0.f;
        for (int i = 0; i < KOUT; ++i) s += sm.selint[i];
        out_tot[b*LO + lo] = s;
    }
}

// Final phase: batchnorm3 (mean over batch) -> integrate -> log_softmax -> f32
__device__ void final_body(void* smem_raw, int b,
    const float* __restrict__ sel3, const float* __restrict__ tot3,
    float* __restrict__ out)
{
    FinalSmem& sm = *reinterpret_cast<FinalSmem*>(smem_raw);
    const int tid = threadIdx.x;
    if (tid < 10) {
        float s = 0.f;
        for (int bb = 0; bb < BATCH; ++bb) s += tot3[bb*10 + tid];
        sm.scale3[tid] = 1.f / (s / (float)BATCH + EPS_F);
    }
    __syncthreads();
    if (tid < 10) {
        float s = 0.f;
        const float* base = sel3 + (size_t)((b*10 + tid)*5)*7;
        for (int kk = 0; kk < 5; ++kk) {
            const float* c = base + kk*7;
            const float det = c[3]*c[6] - c[4]*c[5];
            s += c[0] * sm.scale3[tid] * TWO_PI_F * sqrtf(fmaxf(det, EPS_F));
        }
        sm.integ[tid] = sane(s);
    }
    __syncthreads();
    if (tid == 0) {
        float m = -1e30f;
        for (int l = 0; l < 10; ++l) m = fmaxf(m, sm.integ[l]);
        float ss = 0.f;
        for (int l = 0; l < 10; ++l) ss += __expf(sm.integ[l] - m);
        sm.red2[0] = m; sm.red2[1] = logf(ss);
    }
    __syncthreads();
    if (tid < 10) out[b*10 + tid] = sm.integ[tid] - sm.red2[0] - sm.red2[1];
}

using S1 = LayerSmem<1, 64, 5, 320, 5, 64, 16>;
using S2 = LayerSmem<5, 25, 5, 625, 5, 128, 8>;
using S3 = LayerSmem<6, 12, 5, 360, 6, 64, 16>;
constexpr size_t cmax2(size_t a, size_t b) { return a > b ? a : b; }
constexpr size_t SMEM_MAX = cmax2(cmax2(sizeof(S1), sizeof(S2)),
                                  cmax2(sizeof(S3), sizeof(FinalSmem)));

// Whole net in ONE plain launch. 256 blocks x 1024 threads, LDS ~58.4KB ->
// 1 block/CU on 256 CUs: all blocks co-resident (persistent-kernel sizing),
// so the software grid barrier is sound. Layer 3's 320 units: blocks 0..63
// run a second sequential unit.
__global__ __launch_bounds__(1024) void fused_net(
    const float* __restrict__ in_x,
    const float* __restrict__ k1, const float* __restrict__ k2,
    const float* __restrict__ k3,
    const float* __restrict__ b1, const float* __restrict__ b2,
    const float* __restrict__ b3,
    float* __restrict__ sel1, float* __restrict__ tot1,
    float* __restrict__ sel2, float* __restrict__ tot2,
    float* __restrict__ sel3, float* __restrict__ tot3,
    unsigned int* __restrict__ bar,
    float* __restrict__ out)
{
    __shared__ __align__(16) unsigned char smem[SMEM_MAX];
    const int blk = blockIdx.x;

    // Layer 1: (32,1,64) conv (5,1,5) -> 320 comps, keep 25.  160 blocks.
    if (blk < BATCH*5)
        layer_body<5, 1, 64, 5, 320, 25, 5, 64, 16, true>(
            smem, blk, in_x, nullptr, nullptr, k1, b1, sel1, tot1);
    grid_barrier(bar, 0);

    // Layer 2: (32,5,25) conv (6,5,5) -> 625 comps, keep 12.  192 blocks.
    if (blk < BATCH*6)
        layer_body<6, 5, 25, 5, 625, 12, 5, 128, 8, false>(
            smem, blk, nullptr, sel1, tot1, k2, b2, sel2, tot2);
    grid_barrier(bar, 1);

    // Layer 3: (32,6,12) conv (10,6,5) -> 360 comps, keep 5.  320 units.
    for (int u = blk; u < BATCH*10; u += GRIDB) {
        layer_body<10, 6, 12, 5, 360, 5, 6, 64, 16, false>(
            smem, u, nullptr, sel2, tot2, k3, b3, sel3, tot3);
        __syncthreads();
    }
    grid_barrier(bar, 2);

    // Final: batchnorm + integrate + log_softmax.  32 blocks.
    if (blk < BATCH)
        final_body(smem, blk, sel3, tot3, out);
}

extern "C" void kernel_launch(void* const* d_in, const int* in_sizes, int n_in,
                              void* d_out, int out_size, void* d_ws, size_t ws_size,
                              hipStream_t stream)
{
    const float* in_x = (const float*)d_in[0];
    const float* k1   = (const float*)d_in[1];
    const float* k2   = (const float*)d_in[2];
    const float* k3   = (const float*)d_in[3];
    const float* b1   = (const float*)d_in[4];
    const float* b2   = (const float*)d_in[5];
    const float* b3   = (const float*)d_in[6];
    float* out = (float*)d_out;   // reference output dtype is float32

    float* ws = (float*)d_ws;
    float* sel1 = ws;                  // 32*5*25*7  = 28000 floats
    float* tot1 = ws + 28000;          // 160
    float* sel2 = ws + 28160;          // 32*6*12*7  = 16128
    float* tot2 = ws + 44288;          // 192
    float* sel3 = ws + 44480;          // 32*10*5*7  = 11200
    float* tot3 = ws + 55680;          // 320
    unsigned int* bar = (unsigned int*)(ws + 56064);  // 3 counters, 128B-spread

    // Zero the barrier counters on-stream (graph-capturable; d_ws is poisoned
    // before every timed call, so this must run every call).
    hipMemsetAsync(bar, 0, 3 * 32 * sizeof(unsigned int), stream);

    fused_net<<<GRIDB, 1024, 0, stream>>>(
        in_x, k1, k2, k3, b1, b2, b3,
        sel1, tot1, sel2, tot2, sel3, tot3, bar, out);
}

// Round 10
// 174.081 us; speedup vs baseline: 1.2801x; 1.2801x over previous
//
#include <hip/hip_runtime.h>

#define TWO_PI_F 6.283185307179586f
#define EPS_F 1e-6f
#define LOG2E_F 1.4426950408889634f
#define BATCH 32

// Replace non-finite by 0 (bit test so fast-math can't fold it away).
__device__ __forceinline__ float sane(float x) {
    return ((__float_as_uint(x) & 0x7f800000u) == 0x7f800000u) ? 0.f : x;
}

// ---------------------------------------------------------------------------
// Generic fused layer (round-7 proven): [prev batchnorm] -> gm_convolve ->
// eval_at_centers (poly form, LDS-pipe uniform broadcasts) -> relu_fit
// (stable-rank top-KOUT) -> selected comps + per-(b,lo) abs-integral.
// Used for layers 1 and 3.
// ---------------------------------------------------------------------------
template<int LO, int LI, int ND, int NK, int NCOMP, int KOUT,
         int KP, int TPG, int G, bool FIRST>
__global__ __launch_bounds__(TPG*G) void layer_kernel(
    const float* __restrict__ in_x,
    const float* __restrict__ prev_sel,
    const float* __restrict__ prev_tot,
    const float* __restrict__ kern,
    const float* __restrict__ bias,
    float* __restrict__ out_sel,
    float* __restrict__ out_tot)
{
    constexpr int KUSE   = NCOMP / KP;
    static_assert(KUSE * KP == NCOMP, "exact k tiling required");
    constexpr int CHUNK  = (NCOMP + G - 1) / G;
    constexpr int NCOMP4 = (NCOMP + 3) & ~3;
    constexpr int NQn    = NCOMP4 / 4;
    constexpr int CQ     = (NQn + G - 1) / G;

    const int b   = blockIdx.x / LO;
    const int lo  = blockIdx.x % LO;
    const int tid = threadIdx.x;
    const int g   = tid / TPG;
    const int kt  = tid % TPG;
    const bool active = (kt < KUSE);

    struct StageT {
        float4 d_c[LI*ND];
        float4 k_c[LI*NK];
        float  d_w[LI*ND], d_px[LI*ND], d_py[LI*ND];
        float  k_w[LI*NK], k_px[LI*NK], k_py[LI*NK];
    };
    constexpr size_t ACCB = (size_t)(G > 1 ? (G-1)*TPG*KP : 1) * sizeof(float);
    constexpr size_t UB   = sizeof(StageT) > ACCB ? sizeof(StageT) : ACCB;
    __shared__ __align__(16) unsigned char u_smem[UB];
    StageT& st    = *reinterpret_cast<StageT*>(u_smem);
    float* accbuf = reinterpret_cast<float*>(u_smem);

    __shared__ float2 cPos[NCOMP];
    __shared__ float4 nP[NCOMP];    // a, b, c, d (log2e-folded quadform poly)
    __shared__ float4 nQ[NCOMP];    // e, f, w, 0
    __shared__ float4 cC[NCOMP];
    __shared__ float  w2s[NCOMP];
    __shared__ __align__(16) float a2s[NCOMP4];
    __shared__ float  scr[64];
    __shared__ float  selint[32];
    __shared__ float  dscale[LI];

    if constexpr (FIRST) {
        if (tid < ND) {
            const float* s = in_x + (size_t)(b*ND + tid)*7;
            const float w  = sane(s[0]);
            const float c0 = sane(s[3]), c1 = sane(s[4]), c2 = sane(s[5]), c3 = sane(s[6]);
            st.d_w[tid] = w; st.d_px[tid] = sane(s[1]); st.d_py[tid] = sane(s[2]);
            st.d_c[tid] = make_float4(c0, c1, c2, c3);
            const float det = c0*c3 - c1*c2;
            scr[tid] = sane(fabsf(w) * TWO_PI_F * sqrtf(fmaxf(det, EPS_F)));
        }
        __syncthreads();
        if (tid == 0) {
            float s = 0.f;
            for (int i = 0; i < ND; ++i) s += scr[i];
            dscale[0] = 1.f / (s + EPS_F);
        }
        __syncthreads();
        if (tid < ND) st.d_w[tid] = sane(st.d_w[tid] * dscale[0]);
    } else {
        if (tid < LI) {
            float s = 0.f;
            for (int bb = 0; bb < BATCH; ++bb) s += prev_tot[bb*LI + tid];
            dscale[tid] = 1.f / (s / (float)BATCH + EPS_F);
        }
        __syncthreads();
        if (tid < LI*ND) {
            const int li = tid / ND;
            const float* s = prev_sel + (size_t)(b*LI*ND + tid)*7;
            st.d_w[tid]  = sane(s[0] * dscale[li]);
            st.d_px[tid] = s[1]; st.d_py[tid] = s[2];
            st.d_c[tid]  = make_float4(s[3], s[4], s[5], s[6]);
        }
    }
    if (tid < LI*NK) {
        const float* s = kern + (size_t)(lo*LI*NK + tid)*7;
        st.k_w[tid]  = sane(s[0]);
        st.k_px[tid] = sane(s[1]); st.k_py[tid] = sane(s[2]);
        st.k_c[tid]  = make_float4(sane(s[3]), sane(s[4]), sane(s[5]), sane(s[6]));
    }
    __syncthreads();

    if (tid < NCOMP) {
        const int li = tid / (ND*NK);
        const int r  = tid % (ND*NK);
        const int nd = r / NK, nk = r % NK;
        const int di = li*ND + nd, ki = li*NK + nk;
        const float4 dc = st.d_c[di], kc = st.k_c[ki];
        const float c0 = dc.x + kc.x, c1 = dc.y + kc.y, c2 = dc.z + kc.z, c3 = dc.w + kc.w;
        const float dd = dc.x*dc.w - dc.y*dc.z;
        const float dk = kc.x*kc.w - kc.y*kc.z;
        const float ds = c0*c3 - c1*c2;
        const float w  = sane(st.d_w[di]*st.k_w[ki]*TWO_PI_F*sqrtf(fmaxf(dd*dk, 0.f) / fmaxf(ds, EPS_F)));
        const float px = sane(st.d_px[di] + st.k_px[ki]);
        const float py = sane(st.d_py[di] + st.k_py[ki]);
        const float inv = -0.5f * LOG2E_F / ds;
        const float a   = sane(c3*inv);
        const float bb  = sane(-(c1 + c2)*inv);
        const float cc  = sane(c0*inv);
        const float dd2 = sane(-(2.f*a*px + bb*py));
        const float ee  = sane(-(2.f*cc*py + bb*px));
        const float ff  = sane((a*px + bb*py)*px + cc*py*py);
        cPos[tid] = make_float2(px, py);
        nP[tid]   = make_float4(a, bb, cc, dd2);
        nQ[tid]   = make_float4(ee, ff, w, 0.f);
        cC[tid]   = make_float4(sane(c0), sane(c1), sane(c2), sane(c3));
    }
    __syncthreads();

    float kx[KP], ky[KP], kx2[KP], ky2[KP], kxy[KP], acc[KP];
    #pragma unroll
    for (int j = 0; j < KP; ++j) {
        acc[j] = 0.f; kx[j] = 0.f; ky[j] = 0.f;
        if (active) { const float2 p = cPos[kt + j*KUSE]; kx[j] = p.x; ky[j] = p.y; }
        kx2[j] = kx[j]*kx[j]; ky2[j] = ky[j]*ky[j]; kxy[j] = kx[j]*ky[j];
    }
    {
        const int n0 = g*CHUNK;
        const int n1 = (n0 + CHUNK < NCOMP) ? (n0 + CHUNK) : NCOMP;
        #pragma unroll 2
        for (int n = n0; n < n1; ++n) {
            const float4 P = nP[n];
            const float4 Q = nQ[n];
            #pragma unroll
            for (int j = 0; j < KP; ++j) {
                const float md = fmaf(P.x, kx2[j],
                                 fmaf(P.y, kxy[j],
                                 fmaf(P.z, ky2[j],
                                 fmaf(P.w, kx[j],
                                 fmaf(Q.x, ky[j], Q.y)))));
                acc[j] = fmaf(Q.z, exp2f(md), acc[j]);
            }
        }
    }
    if (g > 0 && active) {
        #pragma unroll
        for (int j = 0; j < KP; ++j) accbuf[((g-1)*TPG + kt)*KP + j] = acc[j];
    }
    __syncthreads();

    const float bi = bias[lo];
    if (g == 0 && active) {
        #pragma unroll
        for (int j = 0; j < KP; ++j) {
            float s = acc[j];
            for (int gg = 1; gg < G; ++gg) s += accbuf[((gg-1)*TPG + kt)*KP + j];
            const float v  = s + bi;
            const float sc = fmaxf(v, 0.f) / (fabsf(v) + EPS_F);
            const int   k  = kt + j*KUSE;
            const float ww = sane(nQ[k].z * sc);
            w2s[k] = ww;
            a2s[k] = fabsf(ww);
        }
    }
    if constexpr (NCOMP4 > NCOMP) {
        if (tid >= NCOMP && tid < NCOMP4) a2s[tid] = -1.f;
    }
    __syncthreads();

    int rank[KP];
    float myv[KP];
    #pragma unroll
    for (int j = 0; j < KP; ++j) rank[j] = 0;
    if (active) {
        #pragma unroll
        for (int j = 0; j < KP; ++j) myv[j] = a2s[kt + j*KUSE];
        const int q0 = g*CQ;
        const int q1 = (q0 + CQ < NQn) ? (q0 + CQ) : NQn;
        for (int q = q0; q < q1; ++q) {
            const float4 v4 = ((const float4*)a2s)[q];
            #pragma unroll
            for (int c = 0; c < 4; ++c) {
                const float vj = (c == 0) ? v4.x : (c == 1) ? v4.y : (c == 2) ? v4.z : v4.w;
                const int   jj = 4*q + c;
                #pragma unroll
                for (int j = 0; j < KP; ++j) {
                    const int myk = kt + j*KUSE;
                    rank[j] += (vj > myv[j] || (vj == myv[j] && jj < myk)) ? 1 : 0;
                }
            }
        }
        if (g > 0) {
            #pragma unroll
            for (int j = 0; j < KP; ++j) accbuf[((g-1)*TPG + kt)*KP + j] = (float)rank[j];
        }
    }
    __syncthreads();

    if (g == 0 && active) {
        #pragma unroll
        for (int j = 0; j < KP; ++j) {
            int r = rank[j];
            for (int gg = 1; gg < G; ++gg) r += (int)accbuf[((gg-1)*TPG + kt)*KP + j];
            if (r < KOUT) {
                const int k = kt + j*KUSE;
                const float2 p = cPos[k];
                const float4 c = cC[k];
                const float ww = w2s[k];
                float* dst = out_sel + (size_t)((b*LO + lo)*KOUT + r)*7;
                dst[0] = ww; dst[1] = p.x; dst[2] = p.y;
                dst[3] = c.x; dst[4] = c.y; dst[5] = c.z; dst[6] = c.w;
                const float det = c.x*c.w - c.y*c.z;
                selint[r] = sane(fabsf(ww) * TWO_PI_F * sqrtf(fmaxf(det, EPS_F)));
            }
        }
    }
    __syncthreads();
    if (tid == 0) {
        float s = 0.f;
        for (int i = 0; i < KOUT; ++i) s += selint[i];
        out_tot[b*LO + lo] = s;
    }
}

// ---------------------------------------------------------------------------
// Layer-2 split, stage A: batchnorm + conv + PARTIAL eval over 1/NSPLIT of n.
// Grid: NSPLIT*BATCH*LO blocks; partial sums (no bias) -> part[blkUnit][k].
// Slim LDS (~43 KB) so the doubled grid gets >1 block/CU co-residency.
// ---------------------------------------------------------------------------
template<int LO, int LI, int ND, int NK, int NCOMP, int KP, int TPG, int G,
         int NSPLIT, int PADK>
__global__ __launch_bounds__(TPG*G) void eval_partial_kernel(
    const float* __restrict__ prev_sel,
    const float* __restrict__ prev_tot,
    const float* __restrict__ kern,
    float* __restrict__ part)          // (NSPLIT*B*LO, PADK)
{
    constexpr int KUSE = NCOMP / KP;
    static_assert(KUSE * KP == NCOMP, "exact k tiling required");
    constexpr int CH2 = (NCOMP + NSPLIT - 1) / NSPLIT;
    constexpr int CHG = (CH2 + G - 1) / G;

    const int unit = blockIdx.x;               // (h*BATCH + b)*LO + lo
    const int h    = unit / (BATCH*LO);
    const int rem  = unit % (BATCH*LO);
    const int b    = rem / LO;
    const int lo   = rem % LO;
    const int tid  = threadIdx.x;
    const int g    = tid / TPG;
    const int kt   = tid % TPG;
    const bool active = (kt < KUSE);

    struct StageT {
        float4 d_c[LI*ND];
        float4 k_c[LI*NK];
        float  d_w[LI*ND], d_px[LI*ND], d_py[LI*ND];
        float  k_w[LI*NK], k_px[LI*NK], k_py[LI*NK];
    };
    constexpr size_t ACCB = (size_t)(G > 1 ? (G-1)*TPG*KP : 1) * sizeof(float);
    constexpr size_t UB   = sizeof(StageT) > ACCB ? sizeof(StageT) : ACCB;
    __shared__ __align__(16) unsigned char u_smem[UB];
    StageT& st    = *reinterpret_cast<StageT*>(u_smem);
    float* accbuf = reinterpret_cast<float*>(u_smem);

    __shared__ float2 cPos[NCOMP];
    __shared__ float4 nP[NCOMP];
    __shared__ float4 nQ[NCOMP];
    __shared__ float  dscale[LI];

    if (tid < LI) {
        float s = 0.f;
        for (int bb = 0; bb < BATCH; ++bb) s += prev_tot[bb*LI + tid];
        dscale[tid] = 1.f / (s / (float)BATCH + EPS_F);
    }
    __syncthreads();
    if (tid < LI*ND) {
        const int li = tid / ND;
        const float* s = prev_sel + (size_t)(b*LI*ND + tid)*7;
        st.d_w[tid]  = sane(s[0] * dscale[li]);
        st.d_px[tid] = s[1]; st.d_py[tid] = s[2];
        st.d_c[tid]  = make_float4(s[3], s[4], s[5], s[6]);
    }
    if (tid < LI*NK) {
        const float* s = kern + (size_t)(lo*LI*NK + tid)*7;
        st.k_w[tid]  = sane(s[0]);
        st.k_px[tid] = sane(s[1]); st.k_py[tid] = sane(s[2]);
        st.k_c[tid]  = make_float4(sane(s[3]), sane(s[4]), sane(s[5]), sane(s[6]));
    }
    __syncthreads();

    if (tid < NCOMP) {
        const int li = tid / (ND*NK);
        const int r  = tid % (ND*NK);
        const int nd = r / NK, nk = r % NK;
        const int di = li*ND + nd, ki = li*NK + nk;
        const float4 dc = st.d_c[di], kc = st.k_c[ki];
        const float c0 = dc.x + kc.x, c1 = dc.y + kc.y, c2 = dc.z + kc.z, c3 = dc.w + kc.w;
        const float dd = dc.x*dc.w - dc.y*dc.z;
        const float dk = kc.x*kc.w - kc.y*kc.z;
        const float ds = c0*c3 - c1*c2;
        const float w  = sane(st.d_w[di]*st.k_w[ki]*TWO_PI_F*sqrtf(fmaxf(dd*dk, 0.f) / fmaxf(ds, EPS_F)));
        const float px = sane(st.d_px[di] + st.k_px[ki]);
        const float py = sane(st.d_py[di] + st.k_py[ki]);
        const float inv = -0.5f * LOG2E_F / ds;
        const float a   = sane(c3*inv);
        const float bb  = sane(-(c1 + c2)*inv);
        const float cc  = sane(c0*inv);
        const float dd2 = sane(-(2.f*a*px + bb*py));
        const float ee  = sane(-(2.f*cc*py + bb*px));
        const float ff  = sane((a*px + bb*py)*px + cc*py*py);
        cPos[tid] = make_float2(px, py);
        nP[tid]   = make_float4(a, bb, cc, dd2);
        nQ[tid]   = make_float4(ee, ff, w, 0.f);
    }
    __syncthreads();

    float kx[KP], ky[KP], kx2[KP], ky2[KP], kxy[KP], acc[KP];
    #pragma unroll
    for (int j = 0; j < KP; ++j) {
        acc[j] = 0.f; kx[j] = 0.f; ky[j] = 0.f;
        if (active) { const float2 p = cPos[kt + j*KUSE]; kx[j] = p.x; ky[j] = p.y; }
        kx2[j] = kx[j]*kx[j]; ky2[j] = ky[j]*ky[j]; kxy[j] = kx[j]*ky[j];
    }
    {
        const int nlo = h*CH2;
        const int nhi = (nlo + CH2 < NCOMP) ? (nlo + CH2) : NCOMP;
        const int n0  = nlo + g*CHG;
        const int n1  = (n0 + CHG < nhi) ? (n0 + CHG) : nhi;
        if (n0 < n1) {
            float4 P = nP[n0], Q = nQ[n0];   // 2-stage register prefetch:
            for (int n = n0; n < n1; ++n) {  // next n's loads issue before the
                const int nn = (n + 1 < n1) ? n + 1 : n0;  // exp chain retires
                const float4 Pn = nP[nn];
                const float4 Qn = nQ[nn];
                #pragma unroll
                for (int j = 0; j < KP; ++j) {
                    const float md = fmaf(P.x, kx2[j],
                                     fmaf(P.y, kxy[j],
                                     fmaf(P.z, ky2[j],
                                     fmaf(P.w, kx[j],
                                     fmaf(Q.x, ky[j], Q.y)))));
                    acc[j] = fmaf(Q.z, exp2f(md), acc[j]);
                }
                P = Pn; Q = Qn;
            }
        }
    }
    if (g > 0 && active) {
        #pragma unroll
        for (int j = 0; j < KP; ++j) accbuf[((g-1)*TPG + kt)*KP + j] = acc[j];
    }
    __syncthreads();
    if (g == 0 && active) {
        float* dst = part + (size_t)unit * PADK;
        #pragma unroll
        for (int j = 0; j < KP; ++j) {
            float s = acc[j];
            for (int gg = 1; gg < G; ++gg) s += accbuf[((gg-1)*TPG + kt)*KP + j];
            dst[kt + j*KUSE] = s;
        }
    }
}

// ---------------------------------------------------------------------------
// Layer-2 split, stage B: redo cheap conv (w/px/py/C only), sum partials +
// bias, relu scale, stable rank, write selected comps + abs-integral.
// Grid: BATCH*LO blocks, TPG*G threads (640).
// ---------------------------------------------------------------------------
template<int LO, int LI, int ND, int NK, int NCOMP, int KOUT, int KP, int TPG,
         int G, int NSPLIT, int PADK>
__global__ __launch_bounds__(TPG*G) void merge_rank_kernel(
    const float* __restrict__ prev_sel,
    const float* __restrict__ prev_tot,
    const float* __restrict__ kern,
    const float* __restrict__ bias,
    const float* __restrict__ part,
    float* __restrict__ out_sel,
    float* __restrict__ out_tot)
{
    constexpr int KUSE   = NCOMP / KP;
    constexpr int NCOMP4 = (NCOMP + 3) & ~3;
    constexpr int NQn    = NCOMP4 / 4;
    constexpr int CQ     = (NQn + G - 1) / G;

    const int b   = blockIdx.x / LO;
    const int lo  = blockIdx.x % LO;
    const int tid = threadIdx.x;
    const int g   = tid / TPG;
    const int kt  = tid % TPG;
    const bool active = (kt < KUSE);

    struct StageT {
        float4 d_c[LI*ND];
        float4 k_c[LI*NK];
        float  d_w[LI*ND], d_px[LI*ND], d_py[LI*ND];
        float  k_w[LI*NK], k_px[LI*NK], k_py[LI*NK];
    };
    constexpr size_t ACCB = (size_t)(G > 1 ? (G-1)*TPG*KP : 1) * sizeof(float);
    constexpr size_t UB   = sizeof(StageT) > ACCB ? sizeof(StageT) : ACCB;
    __shared__ __align__(16) unsigned char u_smem[UB];
    StageT& st    = *reinterpret_cast<StageT*>(u_smem);
    float* accbuf = reinterpret_cast<float*>(u_smem);

    __shared__ float2 cPos[NCOMP];
    __shared__ float4 cC[NCOMP];
    __shared__ float  cw[NCOMP];
    __shared__ float  w2s[NCOMP];
    __shared__ __align__(16) float a2s[NCOMP4];
    __shared__ float  selint[32];
    __shared__ float  dscale[LI];

    if (tid < LI) {
        float s = 0.f;
        for (int bb = 0; bb < BATCH; ++bb) s += prev_tot[bb*LI + tid];
        dscale[tid] = 1.f / (s / (float)BATCH + EPS_F);
    }
    __syncthreads();
    if (tid < LI*ND) {
        const int li = tid / ND;
        const float* s = prev_sel + (size_t)(b*LI*ND + tid)*7;
        st.d_w[tid]  = sane(s[0] * dscale[li]);
        st.d_px[tid] = s[1]; st.d_py[tid] = s[2];
        st.d_c[tid]  = make_float4(s[3], s[4], s[5], s[6]);
    }
    if (tid < LI*NK) {
        const float* s = kern + (size_t)(lo*LI*NK + tid)*7;
        st.k_w[tid]  = sane(s[0]);
        st.k_px[tid] = sane(s[1]); st.k_py[tid] = sane(s[2]);
        st.k_c[tid]  = make_float4(sane(s[3]), sane(s[4]), sane(s[5]), sane(s[6]));
    }
    __syncthreads();

    const float bi = bias[lo];
    if (tid < NCOMP) {
        const int li = tid / (ND*NK);
        const int r  = tid % (ND*NK);
        const int nd = r / NK, nk = r % NK;
        const int di = li*ND + nd, ki = li*NK + nk;
        const float4 dc = st.d_c[di], kc = st.k_c[ki];
        const float c0 = dc.x + kc.x, c1 = dc.y + kc.y, c2 = dc.z + kc.z, c3 = dc.w + kc.w;
        const float dd = dc.x*dc.w - dc.y*dc.z;
        const float dk = kc.x*kc.w - kc.y*kc.z;
        const float ds = c0*c3 - c1*c2;
        const float w  = sane(st.d_w[di]*st.k_w[ki]*TWO_PI_F*sqrtf(fmaxf(dd*dk, 0.f) / fmaxf(ds, EPS_F)));
        cPos[tid] = make_float2(sane(st.d_px[di] + st.k_px[ki]),
                                sane(st.d_py[di] + st.k_py[ki]));
        cC[tid]   = make_float4(sane(c0), sane(c1), sane(c2), sane(c3));
        cw[tid]   = w;
        // sum partials + bias -> relu scale
        float v = bi;
        #pragma unroll
        for (int hh = 0; hh < NSPLIT; ++hh)
            v += part[(size_t)((hh*BATCH + b)*LO + lo) * PADK + tid];
        const float sc = fmaxf(v, 0.f) / (fabsf(v) + EPS_F);
        const float ww = sane(w * sc);
        w2s[tid] = ww;
        a2s[tid] = fabsf(ww);
    }
    if constexpr (NCOMP4 > NCOMP) {
        if (tid >= NCOMP && tid < NCOMP4) a2s[tid] = -1.f;
    }
    __syncthreads();

    int rank[KP];
    float myv[KP];
    #pragma unroll
    for (int j = 0; j < KP; ++j) rank[j] = 0;
    if (active) {
        #pragma unroll
        for (int j = 0; j < KP; ++j) myv[j] = a2s[kt + j*KUSE];
        const int q0 = g*CQ;
        const int q1 = (q0 + CQ < NQn) ? (q0 + CQ) : NQn;
        for (int q = q0; q < q1; ++q) {
            const float4 v4 = ((const float4*)a2s)[q];
            #pragma unroll
            for (int c = 0; c < 4; ++c) {
                const float vj = (c == 0) ? v4.x : (c == 1) ? v4.y : (c == 2) ? v4.z : v4.w;
                const int   jj = 4*q + c;
                #pragma unroll
                for (int j = 0; j < KP; ++j) {
                    const int myk = kt + j*KUSE;
                    rank[j] += (vj > myv[j] || (vj == myv[j] && jj < myk)) ? 1 : 0;
                }
            }
        }
        if (g > 0) {
            #pragma unroll
            for (int j = 0; j < KP; ++j) accbuf[((g-1)*TPG + kt)*KP + j] = (float)rank[j];
        }
    }
    __syncthreads();

    if (g == 0 && active) {
        #pragma unroll
        for (int j = 0; j < KP; ++j) {
            int r = rank[j];
            for (int gg = 1; gg < G; ++gg) r += (int)accbuf[((gg-1)*TPG + kt)*KP + j];
            if (r < KOUT) {
                const int k = kt + j*KUSE;
                const float2 p = cPos[k];
                const float4 c = cC[k];
                const float ww = w2s[k];
                float* dst = out_sel + (size_t)((b*LO + lo)*KOUT + r)*7;
                dst[0] = ww; dst[1] = p.x; dst[2] = p.y;
                dst[3] = c.x; dst[4] = c.y; dst[5] = c.z; dst[6] = c.w;
                const float det = c.x*c.w - c.y*c.z;
                selint[r] = sane(fabsf(ww) * TWO_PI_F * sqrtf(fmaxf(det, EPS_F)));
            }
        }
    }
    __syncthreads();
    if (tid == 0) {
        float s = 0.f;
        for (int i = 0; i < KOUT; ++i) s += selint[i];
        out_tot[b*LO + lo] = s;
    }
}

// Final: batchnorm3 scale (mean over batch) -> integrate -> log_softmax -> f32
__global__ __launch_bounds__(64) void final_kernel(
    const float* __restrict__ sel3,
    const float* __restrict__ tot3,
    float* __restrict__ out)
{
    const int b = blockIdx.x;
    const int tid = threadIdx.x;
    __shared__ float scale3[10], integ[10], red2[2];
    if (tid < 10) {
        float s = 0.f;
        for (int bb = 0; bb < BATCH; ++bb) s += tot3[bb*10 + tid];
        scale3[tid] = 1.f / (s / (float)BATCH + EPS_F);
    }
    __syncthreads();
    if (tid < 10) {
        float s = 0.f;
        const float* base = sel3 + (size_t)((b*10 + tid)*5)*7;
        for (int kk = 0; kk < 5; ++kk) {
            const float* c = base + kk*7;
            const float det = c[3]*c[6] - c[4]*c[5];
            s += c[0] * scale3[tid] * TWO_PI_F * sqrtf(fmaxf(det, EPS_F));
        }
        integ[tid] = sane(s);
    }
    __syncthreads();
    if (tid == 0) {
        float m = -1e30f;
        for (int l = 0; l < 10; ++l) m = fmaxf(m, integ[l]);
        float ss = 0.f;
        for (int l = 0; l < 10; ++l) ss += __expf(integ[l] - m);
        red2[0] = m; red2[1] = logf(ss);
    }
    __syncthreads();
    if (tid < 10) out[b*10 + tid] = integ[tid] - red2[0] - red2[1];
}

extern "C" void kernel_launch(void* const* d_in, const int* in_sizes, int n_in,
                              void* d_out, int out_size, void* d_ws, size_t ws_size,
                              hipStream_t stream)
{
    const float* in_x = (const float*)d_in[0];
    const float* k1   = (const float*)d_in[1];
    const float* k2   = (const float*)d_in[2];
    const float* k3   = (const float*)d_in[3];
    const float* b1   = (const float*)d_in[4];
    const float* b2   = (const float*)d_in[5];
    const float* b3   = (const float*)d_in[6];
    float* out = (float*)d_out;

    float* ws = (float*)d_ws;
    float* sel1 = ws;                  // 32*5*25*7  = 28000 floats
    float* tot1 = ws + 28000;          // 160
    float* sel2 = ws + 28160;          // 32*6*12*7  = 16128
    float* tot2 = ws + 44288;          // 192
    float* sel3 = ws + 44480;          // 32*10*5*7  = 11200
    float* tot3 = ws + 55680;          // 320
    float* part = ws + 56064;          // 2*192*640 = 245760 floats (~983 KB)

    // Layer 1: 320 comps, keep 25.  KP=5, TPG=64, G=16 -> 1024 threads.
    layer_kernel<5, 1, 64, 5, 320, 25, 5, 64, 16, true><<<BATCH*5, 1024, 0, stream>>>(
        in_x, nullptr, nullptr, k1, b1, sel1, tot1);
    // Layer 2a: partial eval, n split in 2.  384 blocks x 1024 (KP=5,TPG=128,G=8).
    eval_partial_kernel<6, 5, 25, 5, 625, 5, 128, 8, 2, 640><<<BATCH*6*2, 1024, 0, stream>>>(
        sel1, tot1, k2, part);
    // Layer 2b: merge + rank + write.  192 blocks x 640 (KP=5,TPG=128,G=5).
    merge_rank_kernel<6, 5, 25, 5, 625, 12, 5, 128, 5, 2, 640><<<BATCH*6, 640, 0, stream>>>(
        sel1, tot1, k2, b2, part, sel2, tot2);
    // Layer 3: 360 comps, keep 5.  KP=6, TPG=64, G=12 -> 768 threads.
    layer_kernel<10, 6, 12, 5, 360, 5, 6, 64, 12, false><<<BATCH*10, 768, 0, stream>>>(
        nullptr, sel2, tot2, k3, b3, sel3, tot3);
    // Final: batchnorm + integrate + log_softmax.
    final_kernel<<<BATCH, 64, 0, stream>>>(sel3, tot3, out);
}

// Round 11
// 149.574 us; speedup vs baseline: 1.4898x; 1.1638x over previous
//
#include <hip/hip_runtime.h>

#define TWO_PI_F 6.283185307179586f
#define EPS_F 1e-6f
#define LOG2E_F 1.4426950408889634f
#define BATCH 32

// Bare v_exp_f32 (2^x). libm exp2f may wrap it with edge-case fixups; the
// harness validates at bf16 granularity so the bare HW op is exact enough.
#if __has_builtin(__builtin_amdgcn_exp2f)
#define EXP2F(x) __builtin_amdgcn_exp2f(x)
#else
#define EXP2F(x) exp2f(x)
#endif

// Replace non-finite by 0 (bit test so fast-math can't fold it away).
__device__ __forceinline__ float sane(float x) {
    return ((__float_as_uint(x) & 0x7f800000u) == 0x7f800000u) ? 0.f : x;
}

// One fused layer: [prev batchnorm] -> gm_convolve -> eval_at_centers
// (polynomial form: md = a*kx^2+b*kxy+c*ky^2+d*kx+e*ky+f, with -0.5*log2e
// folded into a..f at conv time -> 5 FMA + v_exp + acc-FMA per cell) ->
// relu_fit (stable-rank top-KOUT) -> selected comps + per-(b,lo) abs-integral.
//
// Thread layout: NT = TPG*G; t -> (g = t/TPG, kt = t%TPG). Active thread
// (kt < KUSE = NCOMP/KP) owns KP k-slots {kt + j*KUSE} in registers; group g
// sums the n-slice. Per-n data arrives as uniform-address ds_read broadcasts
// (LDS pipe, overlaps VALU — round-6 lesson: readlane moves it onto the VALU
// port and regresses).
template<int LO, int LI, int ND, int NK, int NCOMP, int KOUT,
         int KP, int TPG, int G, bool FIRST>
__global__ __launch_bounds__(TPG*G) void layer_kernel(
    const float* __restrict__ in_x,            // FIRST: (B,1,64,7) f32
    const float* __restrict__ prev_sel,        // !FIRST: (B,LI,ND,7) f32
    const float* __restrict__ prev_tot,        // !FIRST: (B,LI) f32
    const float* __restrict__ kern,            // (LO,LI,NK,7) f32
    const float* __restrict__ bias,            // (LO,) f32
    float* __restrict__ out_sel,               // (B,LO,KOUT,7) f32
    float* __restrict__ out_tot)               // (B,LO) f32
{
    constexpr int KUSE   = NCOMP / KP;
    static_assert(KUSE * KP == NCOMP, "exact k tiling required");
    constexpr int CHUNK  = (NCOMP + G - 1) / G;
    constexpr int NCOMP4 = (NCOMP + 3) & ~3;
    constexpr int NQn    = NCOMP4 / 4;
    constexpr int CQ     = (NQn + G - 1) / G;

    const int b   = blockIdx.x / LO;
    const int lo  = blockIdx.x % LO;
    const int tid = threadIdx.x;
    const int g   = tid / TPG;
    const int kt  = tid % TPG;
    const bool active = (kt < KUSE);

    // Staging arrays (dead after Phase A) union'd with accbuf (live Phase B+).
    struct StageT {
        float4 d_c[LI*ND];
        float4 k_c[LI*NK];
        float  d_w[LI*ND], d_px[LI*ND], d_py[LI*ND];
        float  k_w[LI*NK], k_px[LI*NK], k_py[LI*NK];
    };
    constexpr size_t ACCB = (size_t)(G > 1 ? (G-1)*TPG*KP : 1) * sizeof(float);
    constexpr size_t UB   = sizeof(StageT) > ACCB ? sizeof(StageT) : ACCB;
    __shared__ __align__(16) unsigned char u_smem[UB];
    StageT& st    = *reinterpret_cast<StageT*>(u_smem);
    float* accbuf = reinterpret_cast<float*>(u_smem);

    __shared__ float2 cPos[NCOMP];  // px, py
    __shared__ float4 nP[NCOMP];    // a, b, c, d (log2e-folded quadform poly)
    __shared__ float4 nQ[NCOMP];    // e, f, w, 0
    __shared__ float4 cC[NCOMP];    // C00,C01,C10,C11
    __shared__ float  w2s[NCOMP];
    __shared__ __align__(16) float a2s[NCOMP4];
    __shared__ float  scr[64];
    __shared__ float  selint[32];
    __shared__ float  dscale[LI];

    // ---- Phase pre: incoming batchnorm + stage data/kernel into LDS
    if constexpr (FIRST) {
        // per_gaussian=True batchnorm on raw input (LI==1, ND==64)
        if (tid < ND) {
            const float* s = in_x + (size_t)(b*ND + tid)*7;
            const float w  = sane(s[0]);
            const float c0 = sane(s[3]), c1 = sane(s[4]), c2 = sane(s[5]), c3 = sane(s[6]);
            st.d_w[tid] = w; st.d_px[tid] = sane(s[1]); st.d_py[tid] = sane(s[2]);
            st.d_c[tid] = make_float4(c0, c1, c2, c3);
            const float det = c0*c3 - c1*c2;
            scr[tid] = sane(fabsf(w) * TWO_PI_F * sqrtf(fmaxf(det, EPS_F)));
        }
        __syncthreads();
        if (tid == 0) {
            float s = 0.f;
            for (int i = 0; i < ND; ++i) s += scr[i];
            dscale[0] = 1.f / (s + EPS_F);
        }
        __syncthreads();
        if (tid < ND) st.d_w[tid] = sane(st.d_w[tid] * dscale[0]);
    } else {
        // per_gaussian=False batchnorm: per input channel li, mean over batch
        if (tid < LI) {
            float s = 0.f;
            for (int bb = 0; bb < BATCH; ++bb) s += prev_tot[bb*LI + tid];
            dscale[tid] = 1.f / (s / (float)BATCH + EPS_F);
        }
        __syncthreads();
        if (tid < LI*ND) {
            const int li = tid / ND;
            const float* s = prev_sel + (size_t)(b*LI*ND + tid)*7;
            st.d_w[tid]  = sane(s[0] * dscale[li]);
            st.d_px[tid] = s[1]; st.d_py[tid] = s[2];
            st.d_c[tid]  = make_float4(s[3], s[4], s[5], s[6]);
        }
    }
    if (tid < LI*NK) {
        const float* s = kern + (size_t)(lo*LI*NK + tid)*7;
        st.k_w[tid]  = sane(s[0]);
        st.k_px[tid] = sane(s[1]); st.k_py[tid] = sane(s[2]);
        st.k_c[tid]  = make_float4(sane(s[3]), sane(s[4]), sane(s[5]), sane(s[6]));
    }
    __syncthreads();

    // ---- Phase A: gm_convolve -> poly coefficients in LDS.
    // Flattening matches reference reshape: (li, nd, nk), nk fastest.
    if (tid < NCOMP) {
        const int li = tid / (ND*NK);
        const int r  = tid % (ND*NK);
        const int nd = r / NK, nk = r % NK;
        const int di = li*ND + nd, ki = li*NK + nk;
        const float4 dc = st.d_c[di], kc = st.k_c[ki];
        const float c0 = dc.x + kc.x, c1 = dc.y + kc.y, c2 = dc.z + kc.z, c3 = dc.w + kc.w;
        const float dd = dc.x*dc.w - dc.y*dc.z;
        const float dk = kc.x*kc.w - kc.y*kc.z;
        const float ds = c0*c3 - c1*c2;
        const float w  = sane(st.d_w[di]*st.k_w[ki]*TWO_PI_F*sqrtf(fmaxf(dd*dk, 0.f) / fmaxf(ds, EPS_F)));
        const float px = sane(st.d_px[di] + st.k_px[ki]);
        const float py = sane(st.d_py[di] + st.k_py[ki]);
        const float inv = -0.5f * LOG2E_F / ds;
        const float a   = sane(c3*inv);
        const float bb  = sane(-(c1 + c2)*inv);
        const float cc  = sane(c0*inv);
        const float dd2 = sane(-(2.f*a*px + bb*py));
        const float ee  = sane(-(2.f*cc*py + bb*px));
        const float ff  = sane((a*px + bb*py)*px + cc*py*py);
        cPos[tid] = make_float2(px, py);
        nP[tid]   = make_float4(a, bb, cc, dd2);
        nQ[tid]   = make_float4(ee, ff, w, 0.f);
        cC[tid]   = make_float4(sane(c0), sane(c1), sane(c2), sane(c3));
    }
    __syncthreads();

    // ---- Phase B: eval_at_centers, KP k-slots per thread, n split across G
    float kx[KP], ky[KP], kx2[KP], ky2[KP], kxy[KP], acc[KP];
    #pragma unroll
    for (int j = 0; j < KP; ++j) {
        acc[j] = 0.f; kx[j] = 0.f; ky[j] = 0.f;
        if (active) { const float2 p = cPos[kt + j*KUSE]; kx[j] = p.x; ky[j] = p.y; }
        kx2[j] = kx[j]*kx[j]; ky2[j] = ky[j]*ky[j]; kxy[j] = kx[j]*ky[j];
    }
    {
        const int n0 = g*CHUNK;
        const int n1 = (n0 + CHUNK < NCOMP) ? (n0 + CHUNK) : NCOMP;
        #pragma unroll 2
        for (int n = n0; n < n1; ++n) {
            const float4 P = nP[n];   // uniform-address broadcast (LDS pipe)
            const float4 Q = nQ[n];
            #pragma unroll
            for (int j = 0; j < KP; ++j) {
                const float md = fmaf(P.x, kx2[j],
                                 fmaf(P.y, kxy[j],
                                 fmaf(P.z, ky2[j],
                                 fmaf(P.w, kx[j],
                                 fmaf(Q.x, ky[j], Q.y)))));
                acc[j] = fmaf(Q.z, EXP2F(md), acc[j]);
            }
        }
    }
    if (g > 0 && active) {
        #pragma unroll
        for (int j = 0; j < KP; ++j) accbuf[((g-1)*TPG + kt)*KP + j] = acc[j];
    }
    __syncthreads();

    const float bi = bias[lo];
    if (g == 0 && active) {
        #pragma unroll
        for (int j = 0; j < KP; ++j) {
            float s = acc[j];
            for (int gg = 1; gg < G; ++gg) s += accbuf[((gg-1)*TPG + kt)*KP + j];
            const float v  = s + bi;
            const float sc = fmaxf(v, 0.f) / (fabsf(v) + EPS_F);
            const int   k  = kt + j*KUSE;
            const float ww = sane(nQ[k].z * sc);
            w2s[k] = ww;
            a2s[k] = fabsf(ww);
        }
    }
    if constexpr (NCOMP4 > NCOMP) {
        if (tid >= NCOMP && tid < NCOMP4) a2s[tid] = -1.f;  // pad: never ranks
    }
    __syncthreads();

    // ---- Phase C: stable-descending rank (== jax.lax.top_k order), group-split
    // rank(k) = #{j : a2s[j] > a2s[k]  or  (a2s[j] == a2s[k] and j < k)}
    int rank[KP];
    float myv[KP];
    #pragma unroll
    for (int j = 0; j < KP; ++j) rank[j] = 0;
    if (active) {
        #pragma unroll
        for (int j = 0; j < KP; ++j) myv[j] = a2s[kt + j*KUSE];
        const int q0 = g*CQ;
        const int q1 = (q0 + CQ < NQn) ? (q0 + CQ) : NQn;
        for (int q = q0; q < q1; ++q) {
            const float4 v4 = ((const float4*)a2s)[q];  // broadcast
            #pragma unroll
            for (int c = 0; c < 4; ++c) {
                const float vj = (c == 0) ? v4.x : (c == 1) ? v4.y : (c == 2) ? v4.z : v4.w;
                const int   jj = 4*q + c;
                #pragma unroll
                for (int j = 0; j < KP; ++j) {
                    const int myk = kt + j*KUSE;
                    rank[j] += (vj > myv[j] || (vj == myv[j] && jj < myk)) ? 1 : 0;
                }
            }
        }
        if (g > 0) {
            #pragma unroll
            for (int j = 0; j < KP; ++j) accbuf[((g-1)*TPG + kt)*KP + j] = (float)rank[j];
        }
    }
    __syncthreads();

    // ---- Phase D: g==0 finalizes ranks, writes selected comps + integrals
    if (g == 0 && active) {
        #pragma unroll
        for (int j = 0; j < KP; ++j) {
            int r = rank[j];
            for (int gg = 1; gg < G; ++gg) r += (int)accbuf[((gg-1)*TPG + kt)*KP + j];
            if (r < KOUT) {
                const int k = kt + j*KUSE;
                const float2 p = cPos[k];
                const float4 c = cC[k];
                const float ww = w2s[k];
                float* dst = out_sel + (size_t)((b*LO + lo)*KOUT + r)*7;
                dst[0] = ww; dst[1] = p.x; dst[2] = p.y;
                dst[3] = c.x; dst[4] = c.y; dst[5] = c.z; dst[6] = c.w;
                const float det = c.x*c.w - c.y*c.z;
                selint[r] = sane(fabsf(ww) * TWO_PI_F * sqrtf(fmaxf(det, EPS_F)));
            }
        }
    }
    __syncthreads();
    if (tid == 0) {
        float s = 0.f;
        for (int i = 0; i < KOUT; ++i) s += selint[i];
        out_tot[b*LO + lo] = s;
    }
}

// Final: batchnorm3 scale (mean over batch) -> integrate -> log_softmax -> f32
__global__ __launch_bounds__(64) void final_kernel(
    const float* __restrict__ sel3,   // (B,10,5,7)
    const float* __restrict__ tot3,   // (B,10)
    float* __restrict__ out)          // (B,10) f32
{
    const int b = blockIdx.x;
    const int tid = threadIdx.x;
    __shared__ float scale3[10], integ[10], red2[2];
    if (tid < 10) {
        float s = 0.f;
        for (int bb = 0; bb < BATCH; ++bb) s += tot3[bb*10 + tid];
        scale3[tid] = 1.f / (s / (float)BATCH + EPS_F);
    }
    __syncthreads();
    if (tid < 10) {
        float s = 0.f;
        const float* base = sel3 + (size_t)((b*10 + tid)*5)*7;
        for (int kk = 0; kk < 5; ++kk) {
            const float* c = base + kk*7;
            const float det = c[3]*c[6] - c[4]*c[5];
            s += c[0] * scale3[tid] * TWO_PI_F * sqrtf(fmaxf(det, EPS_F));
        }
        integ[tid] = sane(s);
    }
    __syncthreads();
    if (tid == 0) {
        float m = -1e30f;
        for (int l = 0; l < 10; ++l) m = fmaxf(m, integ[l]);
        float ss = 0.f;
        for (int l = 0; l < 10; ++l) ss += __expf(integ[l] - m);
        red2[0] = m; red2[1] = logf(ss);
    }
    __syncthreads();
    if (tid < 10) out[b*10 + tid] = integ[tid] - red2[0] - red2[1];
}

extern "C" void kernel_launch(void* const* d_in, const int* in_sizes, int n_in,
                              void* d_out, int out_size, void* d_ws, size_t ws_size,
                              hipStream_t stream)
{
    const float* in_x = (const float*)d_in[0];
    const float* k1   = (const float*)d_in[1];
    const float* k2   = (const float*)d_in[2];
    const float* k3   = (const float*)d_in[3];
    const float* b1   = (const float*)d_in[4];
    const float* b2   = (const float*)d_in[5];
    const float* b3   = (const float*)d_in[6];
    float* out = (float*)d_out;   // reference output dtype is float32

    float* ws = (float*)d_ws;
    float* sel1 = ws;                  // 32*5*25*7  = 28000 floats
    float* tot1 = ws + 28000;          // 160
    float* sel2 = ws + 28160;          // 32*6*12*7  = 16128
    float* tot2 = ws + 44288;          // 192
    float* sel3 = ws + 44480;          // 32*10*5*7  = 11200
    float* tot3 = ws + 55680;          // 320  (total ~224 KB)

    // Layer 1: 320 comps, keep 25.  KP=5 (64*5=320), TPG=64, G=16 -> NT=1024.
    layer_kernel<5, 1, 64, 5, 320, 25, 5, 64, 16, true><<<BATCH*5, 1024, 0, stream>>>(
        in_x, nullptr, nullptr, k1, b1, sel1, tot1);
    // Layer 2: 625 comps, keep 12.  KP=5 (125*5=625), TPG=128, G=8 -> NT=1024.
    layer_kernel<6, 5, 25, 5, 625, 12, 5, 128, 8, false><<<BATCH*6, 1024, 0, stream>>>(
        nullptr, sel1, tot1, k2, b2, sel2, tot2);
    // Layer 3: 360 comps, keep 5.   KP=6 (60*6=360), TPG=64, G=12 -> NT=768.
    layer_kernel<10, 6, 12, 5, 360, 5, 6, 64, 12, false><<<BATCH*10, 768, 0, stream>>>(
        nullptr, sel2, tot2, k3, b3, sel3, tot3);
    // Final: batchnorm + integrate + log_softmax.
    final_kernel<<<BATCH, 64, 0, stream>>>(sel3, tot3, out);
}

// Round 12
// 147.086 us; speedup vs baseline: 1.5150x; 1.0169x over previous
//
#include <hip/hip_runtime.h>

#define TWO_PI_F 6.283185307179586f
#define EPS_F 1e-6f
#define LOG2E_F 1.4426950408889634f
#define BATCH 32

// Bare v_exp_f32 (2^x). libm exp2f wraps it with edge-case fixups (round-11
// measured: -11 us on layer 2 from dropping the wrapper).
#if __has_builtin(__builtin_amdgcn_exp2f)
#define EXP2F(x) __builtin_amdgcn_exp2f(x)
#else
#define EXP2F(x) exp2f(x)
#endif

typedef float v2f __attribute__((ext_vector_type(2)));

// Replace non-finite by 0 (bit test so fast-math can't fold it away).
__device__ __forceinline__ float sane(float x) {
    return ((__float_as_uint(x) & 0x7f800000u) == 0x7f800000u) ? 0.f : x;
}

// One fused layer: [prev batchnorm] -> gm_convolve -> eval_at_centers
// (polynomial form, k-slots paired into float2 for v_pk_fma_f32 dual-issue)
// -> relu_fit (stable-rank top-KOUT) -> selected comps + abs-integral.
//
// Thread layout: NT = TPG*G; t -> (g = t/TPG, kt = t%TPG). Active thread
// (kt < KUSE = NCOMP/KP) owns KP k-slots {kt + j*KUSE}; group g sums its
// n-slice. Per-n data arrives as uniform-address ds_read broadcasts (LDS
// pipe, overlaps VALU; round-6 lesson: readlane regresses).
template<int LO, int LI, int ND, int NK, int NCOMP, int KOUT,
         int KP, int TPG, int G, bool FIRST>
__global__ __launch_bounds__(TPG*G) void layer_kernel(
    const float* __restrict__ in_x,            // FIRST: (B,1,64,7) f32
    const float* __restrict__ prev_sel,        // !FIRST: (B,LI,ND,7) f32
    const float* __restrict__ prev_tot,        // !FIRST: (B,LI) f32
    const float* __restrict__ kern,            // (LO,LI,NK,7) f32
    const float* __restrict__ bias,            // (LO,) f32
    float* __restrict__ out_sel,               // (B,LO,KOUT,7) f32
    float* __restrict__ out_tot)               // (B,LO) f32
{
    constexpr int KUSE   = NCOMP / KP;
    static_assert(KUSE * KP == NCOMP, "exact k tiling required");
    constexpr int CHUNK  = (NCOMP + G - 1) / G;
    constexpr int NCOMP4 = (NCOMP + 3) & ~3;
    constexpr int NQn    = NCOMP4 / 4;
    constexpr int CQ     = (NQn + G - 1) / G;
    constexpr int NPAIR  = KP / 2;
    constexpr int PPAD   = NPAIR > 0 ? NPAIR : 1;
    constexpr bool ODD   = (KP & 1) != 0;

    const int b   = blockIdx.x / LO;
    const int lo  = blockIdx.x % LO;
    const int tid = threadIdx.x;
    const int g   = tid / TPG;
    const int kt  = tid % TPG;
    const bool active = (kt < KUSE);

    // Staging arrays (dead after Phase A) union'd with accbuf (live Phase B+).
    struct StageT {
        float4 d_c[LI*ND];
        float4 k_c[LI*NK];
        float  d_w[LI*ND], d_px[LI*ND], d_py[LI*ND];
        float  k_w[LI*NK], k_px[LI*NK], k_py[LI*NK];
    };
    constexpr size_t ACCB = (size_t)(G > 1 ? (G-1)*TPG*KP : 1) * sizeof(float);
    constexpr size_t UB   = sizeof(StageT) > ACCB ? sizeof(StageT) : ACCB;
    __shared__ __align__(16) unsigned char u_smem[UB];
    StageT& st    = *reinterpret_cast<StageT*>(u_smem);
    float* accbuf = reinterpret_cast<float*>(u_smem);

    __shared__ float2 cPos[NCOMP];  // px, py
    __shared__ float4 nP[NCOMP];    // a, b, c, d (log2e-folded quadform poly)
    __shared__ float4 nQ[NCOMP];    // e, f, w, 0
    __shared__ float4 cC[NCOMP];    // C00,C01,C10,C11
    __shared__ float  w2s[NCOMP];
    __shared__ __align__(16) float a2s[NCOMP4];
    __shared__ float  scr[64];
    __shared__ float  selint[32];
    __shared__ float  dscale[LI];

    // ---- Phase pre: incoming batchnorm + stage data/kernel into LDS
    if constexpr (FIRST) {
        if (tid < ND) {
            const float* s = in_x + (size_t)(b*ND + tid)*7;
            const float w  = sane(s[0]);
            const float c0 = sane(s[3]), c1 = sane(s[4]), c2 = sane(s[5]), c3 = sane(s[6]);
            st.d_w[tid] = w; st.d_px[tid] = sane(s[1]); st.d_py[tid] = sane(s[2]);
            st.d_c[tid] = make_float4(c0, c1, c2, c3);
            const float det = c0*c3 - c1*c2;
            scr[tid] = sane(fabsf(w) * TWO_PI_F * sqrtf(fmaxf(det, EPS_F)));
        }
        __syncthreads();
        if (tid == 0) {
            float s = 0.f;
            for (int i = 0; i < ND; ++i) s += scr[i];
            dscale[0] = 1.f / (s + EPS_F);
        }
        __syncthreads();
        if (tid < ND) st.d_w[tid] = sane(st.d_w[tid] * dscale[0]);
    } else {
        if (tid < LI) {
            float s = 0.f;
            for (int bb = 0; bb < BATCH; ++bb) s += prev_tot[bb*LI + tid];
            dscale[tid] = 1.f / (s / (float)BATCH + EPS_F);
        }
        __syncthreads();
        if (tid < LI*ND) {
            const int li = tid / ND;
            const float* s = prev_sel + (size_t)(b*LI*ND + tid)*7;
            st.d_w[tid]  = sane(s[0] * dscale[li]);
            st.d_px[tid] = s[1]; st.d_py[tid] = s[2];
            st.d_c[tid]  = make_float4(s[3], s[4], s[5], s[6]);
        }
    }
    if (tid < LI*NK) {
        const float* s = kern + (size_t)(lo*LI*NK + tid)*7;
        st.k_w[tid]  = sane(s[0]);
        st.k_px[tid] = sane(s[1]); st.k_py[tid] = sane(s[2]);
        st.k_c[tid]  = make_float4(sane(s[3]), sane(s[4]), sane(s[5]), sane(s[6]));
    }
    __syncthreads();

    // ---- Phase A: gm_convolve -> poly coefficients in LDS.
    // Flattening matches reference reshape: (li, nd, nk), nk fastest.
    if (tid < NCOMP) {
        const int li = tid / (ND*NK);
        const int r  = tid % (ND*NK);
        const int nd = r / NK, nk = r % NK;
        const int di = li*ND + nd, ki = li*NK + nk;
        const float4 dc = st.d_c[di], kc = st.k_c[ki];
        const float c0 = dc.x + kc.x, c1 = dc.y + kc.y, c2 = dc.z + kc.z, c3 = dc.w + kc.w;
        const float dd = dc.x*dc.w - dc.y*dc.z;
        const float dk = kc.x*kc.w - kc.y*kc.z;
        const float ds = c0*c3 - c1*c2;
        const float w  = sane(st.d_w[di]*st.k_w[ki]*TWO_PI_F*sqrtf(fmaxf(dd*dk, 0.f) / fmaxf(ds, EPS_F)));
        const float px = sane(st.d_px[di] + st.k_px[ki]);
        const float py = sane(st.d_py[di] + st.k_py[ki]);
        const float inv = -0.5f * LOG2E_F / ds;
        const float a   = sane(c3*inv);
        const float bb  = sane(-(c1 + c2)*inv);
        const float cc  = sane(c0*inv);
        const float dd2 = sane(-(2.f*a*px + bb*py));
        const float ee  = sane(-(2.f*cc*py + bb*px));
        const float ff  = sane((a*px + bb*py)*px + cc*py*py);
        cPos[tid] = make_float2(px, py);
        nP[tid]   = make_float4(a, bb, cc, dd2);
        nQ[tid]   = make_float4(ee, ff, w, 0.f);
        cC[tid]   = make_float4(sane(c0), sane(c1), sane(c2), sane(c3));
    }
    __syncthreads();

    // ---- Phase B: eval_at_centers. k-slots paired into float2 so the 5-FMA
    // chain lowers to v_pk_fma_f32 (2 cells/inst); exp stays scalar v_exp.
    v2f kxP[PPAD], kyP[PPAD], kx2P[PPAD], ky2P[PPAD], kxyP[PPAD], accP[PPAD];
    float kxS = 0.f, kyS = 0.f, kx2S = 0.f, ky2S = 0.f, kxyS = 0.f, accS = 0.f;
    #pragma unroll
    for (int p = 0; p < NPAIR; ++p) {
        float x0 = 0.f, y0 = 0.f, x1 = 0.f, y1 = 0.f;
        if (active) {
            const float2 p0 = cPos[kt + (2*p    )*KUSE];
            const float2 p1 = cPos[kt + (2*p + 1)*KUSE];
            x0 = p0.x; y0 = p0.y; x1 = p1.x; y1 = p1.y;
        }
        v2f kx; kx.x = x0; kx.y = x1;
        v2f ky; ky.x = y0; ky.y = y1;
        kxP[p] = kx; kyP[p] = ky;
        kx2P[p] = kx*kx; ky2P[p] = ky*ky; kxyP[p] = kx*ky;
        v2f z; z.x = 0.f; z.y = 0.f; accP[p] = z;
    }
    if constexpr (ODD) {
        if (active) { const float2 pz = cPos[kt + (KP-1)*KUSE]; kxS = pz.x; kyS = pz.y; }
        kx2S = kxS*kxS; ky2S = kyS*kyS; kxyS = kxS*kyS;
    }
    {
        const int n0 = g*CHUNK;
        const int n1 = (n0 + CHUNK < NCOMP) ? (n0 + CHUNK) : NCOMP;
        #pragma unroll 2
        for (int n = n0; n < n1; ++n) {
            const float4 P = nP[n];   // uniform-address broadcast (LDS pipe)
            const float4 Q = nQ[n];
            v2f Pa; Pa.x = P.x; Pa.y = P.x;
            v2f Pb; Pb.x = P.y; Pb.y = P.y;
            v2f Pc; Pc.x = P.z; Pc.y = P.z;
            v2f Pd; Pd.x = P.w; Pd.y = P.w;
            v2f Qe; Qe.x = Q.x; Qe.y = Q.x;
            v2f Qf; Qf.x = Q.y; Qf.y = Q.y;
            v2f Qw; Qw.x = Q.z; Qw.y = Q.z;
            #pragma unroll
            for (int p = 0; p < NPAIR; ++p) {
                const v2f md = __builtin_elementwise_fma(Pa, kx2P[p],
                               __builtin_elementwise_fma(Pb, kxyP[p],
                               __builtin_elementwise_fma(Pc, ky2P[p],
                               __builtin_elementwise_fma(Pd, kxP[p],
                               __builtin_elementwise_fma(Qe, kyP[p], Qf)))));
                v2f ex; ex.x = EXP2F(md.x); ex.y = EXP2F(md.y);
                accP[p] = __builtin_elementwise_fma(Qw, ex, accP[p]);
            }
            if constexpr (ODD) {
                const float md = fmaf(P.x, kx2S,
                                 fmaf(P.y, kxyS,
                                 fmaf(P.z, ky2S,
                                 fmaf(P.w, kxS,
                                 fmaf(Q.x, kyS, Q.y)))));
                accS = fmaf(Q.z, EXP2F(md), accS);
            }
        }
    }
    // Unpack pairs back to per-slot acc[]
    float acc[KP];
    #pragma unroll
    for (int p = 0; p < NPAIR; ++p) { acc[2*p] = accP[p].x; acc[2*p+1] = accP[p].y; }
    if constexpr (ODD) acc[KP-1] = accS;

    if (g > 0 && active) {
        #pragma unroll
        for (int j = 0; j < KP; ++j) accbuf[((g-1)*TPG + kt)*KP + j] = acc[j];
    }
    __syncthreads();

    const float bi = bias[lo];
    if (g == 0 && active) {
        #pragma unroll
        for (int j = 0; j < KP; ++j) {
            float s = acc[j];
            for (int gg = 1; gg < G; ++gg) s += accbuf[((gg-1)*TPG + kt)*KP + j];
            const float v  = s + bi;
            const float sc = fmaxf(v, 0.f) / (fabsf(v) + EPS_F);
            const int   k  = kt + j*KUSE;
            const float ww = sane(nQ[k].z * sc);
            w2s[k] = ww;
            a2s[k] = fabsf(ww);
        }
    }
    if constexpr (NCOMP4 > NCOMP) {
        if (tid >= NCOMP && tid < NCOMP4) a2s[tid] = -1.f;  // pad: never ranks
    }
    __syncthreads();

    // ---- Phase C: stable-descending rank (== jax.lax.top_k order), group-split
    int rank[KP];
    float myv[KP];
    #pragma unroll
    for (int j = 0; j < KP; ++j) rank[j] = 0;
    if (active) {
        #pragma unroll
        for (int j = 0; j < KP; ++j) myv[j] = a2s[kt + j*KUSE];
        const int q0 = g*CQ;
        const int q1 = (q0 + CQ < NQn) ? (q0 + CQ) : NQn;
        for (int q = q0; q < q1; ++q) {
            const float4 v4 = ((const float4*)a2s)[q];  // broadcast
            #pragma unroll
            for (int c = 0; c < 4; ++c) {
                const float vj = (c == 0) ? v4.x : (c == 1) ? v4.y : (c == 2) ? v4.z : v4.w;
                const int   jj = 4*q + c;
                #pragma unroll
                for (int j = 0; j < KP; ++j) {
                    const int myk = kt + j*KUSE;
                    rank[j] += (vj > myv[j] || (vj == myv[j] && jj < myk)) ? 1 : 0;
                }
            }
        }
        if (g > 0) {
            #pragma unroll
            for (int j = 0; j < KP; ++j) accbuf[((g-1)*TPG + kt)*KP + j] = (float)rank[j];
        }
    }
    __syncthreads();

    // ---- Phase D: g==0 finalizes ranks, writes selected comps + integrals
    if (g == 0 && active) {
        #pragma unroll
        for (int j = 0; j < KP; ++j) {
            int r = rank[j];
            for (int gg = 1; gg < G; ++gg) r += (int)accbuf[((gg-1)*TPG + kt)*KP + j];
            if (r < KOUT) {
                const int k = kt + j*KUSE;
                const float2 p = cPos[k];
                const float4 c = cC[k];
                const float ww = w2s[k];
                float* dst = out_sel + (size_t)((b*LO + lo)*KOUT + r)*7;
                dst[0] = ww; dst[1] = p.x; dst[2] = p.y;
                dst[3] = c.x; dst[4] = c.y; dst[5] = c.z; dst[6] = c.w;
                const float det = c.x*c.w - c.y*c.z;
                selint[r] = sane(fabsf(ww) * TWO_PI_F * sqrtf(fmaxf(det, EPS_F)));
            }
        }
    }
    __syncthreads();
    if (tid == 0) {
        float s = 0.f;
        for (int i = 0; i < KOUT; ++i) s += selint[i];
        out_tot[b*LO + lo] = s;
    }
}

// Final: batchnorm3 scale (mean over batch) -> integrate -> log_softmax -> f32
__global__ __launch_bounds__(64) void final_kernel(
    const float* __restrict__ sel3,   // (B,10,5,7)
    const float* __restrict__ tot3,   // (B,10)
    float* __restrict__ out)          // (B,10) f32
{
    const int b = blockIdx.x;
    const int tid = threadIdx.x;
    __shared__ float scale3[10], integ[10], red2[2];
    if (tid < 10) {
        float s = 0.f;
        for (int bb = 0; bb < BATCH; ++bb) s += tot3[bb*10 + tid];
        scale3[tid] = 1.f / (s / (float)BATCH + EPS_F);
    }
    __syncthreads();
    if (tid < 10) {
        float s = 0.f;
        const float* base = sel3 + (size_t)((b*10 + tid)*5)*7;
        for (int kk = 0; kk < 5; ++kk) {
            const float* c = base + kk*7;
            const float det = c[3]*c[6] - c[4]*c[5];
            s += c[0] * scale3[tid] * TWO_PI_F * sqrtf(fmaxf(det, EPS_F));
        }
        integ[tid] = sane(s);
    }
    __syncthreads();
    if (tid == 0) {
        float m = -1e30f;
        for (int l = 0; l < 10; ++l) m = fmaxf(m, integ[l]);
        float ss = 0.f;
        for (int l = 0; l < 10; ++l) ss += __expf(integ[l] - m);
        red2[0] = m; red2[1] = logf(ss);
    }
    __syncthreads();
    if (tid < 10) out[b*10 + tid] = integ[tid] - red2[0] - red2[1];
}

extern "C" void kernel_launch(void* const* d_in, const int* in_sizes, int n_in,
                              void* d_out, int out_size, void* d_ws, size_t ws_size,
                              hipStream_t stream)
{
    const float* in_x = (const float*)d_in[0];
    const float* k1   = (const float*)d_in[1];
    const float* k2   = (const float*)d_in[2];
    const float* k3   = (const float*)d_in[3];
    const float* b1   = (const float*)d_in[4];
    const float* b2   = (const float*)d_in[5];
    const float* b3   = (const float*)d_in[6];
    float* out = (float*)d_out;   // reference output dtype is float32

    float* ws = (float*)d_ws;
    float* sel1 = ws;                  // 32*5*25*7  = 28000 floats
    float* tot1 = ws + 28000;          // 160
    float* sel2 = ws + 28160;          // 32*6*12*7  = 16128
    float* tot2 = ws + 44288;          // 192
    float* sel3 = ws + 44480;          // 32*10*5*7  = 11200
    float* tot3 = ws + 55680;          // 320  (total ~224 KB)

    // Layer 1: 320 comps, keep 25.  KP=5 (64*5=320), TPG=64, G=16 -> NT=1024.
    layer_kernel<5, 1, 64, 5, 320, 25, 5, 64, 16, true><<<BATCH*5, 1024, 0, stream>>>(
        in_x, nullptr, nullptr, k1, b1, sel1, tot1);
    // Layer 2: 625 comps, keep 12.  KP=5 (125*5=625), TPG=128, G=8 -> NT=1024.
    layer_kernel<6, 5, 25, 5, 625, 12, 5, 128, 8, false><<<BATCH*6, 1024, 0, stream>>>(
        nullptr, sel1, tot1, k2, b2, sel2, tot2);
    // Layer 3: 360 comps, keep 5.   KP=6 (60*6=360), TPG=64, G=12 -> NT=768.
    layer_kernel<10, 6, 12, 5, 360, 5, 6, 64, 12, false><<<BATCH*10, 768, 0, stream>>>(
        nullptr, sel2, tot2, k3, b3, sel3, tot3);
    // Final: batchnorm + integrate + log_softmax.
    final_kernel<<<BATCH, 64, 0, stream>>>(sel3, tot3, out);
}

// Round 13
// 146.522 us; speedup vs baseline: 1.5209x; 1.0038x over previous
//
#include <hip/hip_runtime.h>

#define TWO_PI_F 6.283185307179586f
#define EPS_F 1e-6f
#define LOG2E_F 1.4426950408889634f
#define BATCH 32

// Bare v_exp_f32 (2^x). libm exp2f wraps it with edge-case fixups (round-11
// measured: -11 us on layer 2 from dropping the wrapper).
#if __has_builtin(__builtin_amdgcn_exp2f)
#define EXP2F(x) __builtin_amdgcn_exp2f(x)
#else
#define EXP2F(x) exp2f(x)
#endif

typedef float v2f __attribute__((ext_vector_type(2)));

// Replace non-finite by 0 (bit test so fast-math can't fold it away).
__device__ __forceinline__ float sane(float x) {
    return ((__float_as_uint(x) & 0x7f800000u) == 0x7f800000u) ? 0.f : x;
}

// One fused layer: [prev batchnorm] -> gm_convolve -> eval_at_centers
// (polynomial form, k-slots paired for v_pk_fma_f32, 2-deep software-pipelined
// LDS broadcast) -> relu_fit (stable-rank top-KOUT) -> selected comps +
// per-(b,lo) abs-integral.
template<int LO, int LI, int ND, int NK, int NCOMP, int KOUT,
         int KP, int TPG, int G, bool FIRST>
__global__ __launch_bounds__(TPG*G) void layer_kernel(
    const float* __restrict__ in_x,            // FIRST: (B,1,64,7) f32
    const float* __restrict__ prev_sel,        // !FIRST: (B,LI,ND,7) f32
    const float* __restrict__ prev_tot,        // !FIRST: (B,LI) f32
    const float* __restrict__ kern,            // (LO,LI,NK,7) f32
    const float* __restrict__ bias,            // (LO,) f32
    float* __restrict__ out_sel,               // (B,LO,KOUT,7) f32
    float* __restrict__ out_tot)               // (B,LO) f32
{
    constexpr int KUSE   = NCOMP / KP;
    static_assert(KUSE * KP == NCOMP, "exact k tiling required");
    constexpr int CHUNK  = (NCOMP + G - 1) / G;
    constexpr int NCOMP4 = (NCOMP + 3) & ~3;
    constexpr int NQn    = NCOMP4 / 4;
    constexpr int CQ     = (NQn + G - 1) / G;
    constexpr int NPAIR  = KP / 2;
    constexpr int PPAD   = NPAIR > 0 ? NPAIR : 1;
    constexpr bool ODD   = (KP & 1) != 0;

    const int b   = blockIdx.x / LO;
    const int lo  = blockIdx.x % LO;
    const int tid = threadIdx.x;
    const int g   = tid / TPG;
    const int kt  = tid % TPG;
    const bool active = (kt < KUSE);

    // Staging arrays (dead after Phase A) union'd with accbuf (live Phase B+).
    struct StageT {
        float4 d_c[LI*ND];
        float4 k_c[LI*NK];
        float  d_w[LI*ND], d_px[LI*ND], d_py[LI*ND];
        float  k_w[LI*NK], k_px[LI*NK], k_py[LI*NK];
    };
    constexpr size_t ACCB = (size_t)(G > 1 ? (G-1)*TPG*KP : 1) * sizeof(float);
    constexpr size_t UB   = sizeof(StageT) > ACCB ? sizeof(StageT) : ACCB;
    __shared__ __align__(16) unsigned char u_smem[UB];
    StageT& st    = *reinterpret_cast<StageT*>(u_smem);
    float* accbuf = reinterpret_cast<float*>(u_smem);

    __shared__ float2 cPos[NCOMP];  // px, py
    __shared__ float4 nP[NCOMP];    // a, b, c, d (log2e-folded quadform poly)
    __shared__ float4 nQ[NCOMP];    // e, f, w, 0
    __shared__ float4 cC[NCOMP];    // C00,C01,C10,C11
    __shared__ float  w2s[NCOMP];
    __shared__ __align__(16) float a2s[NCOMP4];
    __shared__ float  scr[64];
    __shared__ float  selint[32];
    __shared__ float  dscale[LI];

    // ---- Phase pre: incoming batchnorm + stage data/kernel into LDS
    if constexpr (FIRST) {
        if (tid < ND) {
            const float* s = in_x + (size_t)(b*ND + tid)*7;
            const float w  = sane(s[0]);
            const float c0 = sane(s[3]), c1 = sane(s[4]), c2 = sane(s[5]), c3 = sane(s[6]);
            st.d_w[tid] = w; st.d_px[tid] = sane(s[1]); st.d_py[tid] = sane(s[2]);
            st.d_c[tid] = make_float4(c0, c1, c2, c3);
            const float det = c0*c3 - c1*c2;
            scr[tid] = sane(fabsf(w) * TWO_PI_F * sqrtf(fmaxf(det, EPS_F)));
        }
        __syncthreads();
        if (tid == 0) {
            float s = 0.f;
            for (int i = 0; i < ND; ++i) s += scr[i];
            dscale[0] = 1.f / (s + EPS_F);
        }
        __syncthreads();
        if (tid < ND) st.d_w[tid] = sane(st.d_w[tid] * dscale[0]);
    } else {
        if (tid < LI) {
            float s = 0.f;
            for (int bb = 0; bb < BATCH; ++bb) s += prev_tot[bb*LI + tid];
            dscale[tid] = 1.f / (s / (float)BATCH + EPS_F);
        }
        __syncthreads();
        if (tid < LI*ND) {
            const int li = tid / ND;
            const float* s = prev_sel + (size_t)(b*LI*ND + tid)*7;
            st.d_w[tid]  = sane(s[0] * dscale[li]);
            st.d_px[tid] = s[1]; st.d_py[tid] = s[2];
            st.d_c[tid]  = make_float4(s[3], s[4], s[5], s[6]);
        }
    }
    if (tid < LI*NK) {
        const float* s = kern + (size_t)(lo*LI*NK + tid)*7;
        st.k_w[tid]  = sane(s[0]);
        st.k_px[tid] = sane(s[1]); st.k_py[tid] = sane(s[2]);
        st.k_c[tid]  = make_float4(sane(s[3]), sane(s[4]), sane(s[5]), sane(s[6]));
    }
    __syncthreads();

    // ---- Phase A: gm_convolve -> poly coefficients in LDS.
    // Flattening matches reference reshape: (li, nd, nk), nk fastest.
    if (tid < NCOMP) {
        const int li = tid / (ND*NK);
        const int r  = tid % (ND*NK);
        const int nd = r / NK, nk = r % NK;
        const int di = li*ND + nd, ki = li*NK + nk;
        const float4 dc = st.d_c[di], kc = st.k_c[ki];
        const float c0 = dc.x + kc.x, c1 = dc.y + kc.y, c2 = dc.z + kc.z, c3 = dc.w + kc.w;
        const float dd = dc.x*dc.w - dc.y*dc.z;
        const float dk = kc.x*kc.w - kc.y*kc.z;
        const float ds = c0*c3 - c1*c2;
        const float w  = sane(st.d_w[di]*st.k_w[ki]*TWO_PI_F*sqrtf(fmaxf(dd*dk, 0.f) / fmaxf(ds, EPS_F)));
        const float px = sane(st.d_px[di] + st.k_px[ki]);
        const float py = sane(st.d_py[di] + st.k_py[ki]);
        const float inv = -0.5f * LOG2E_F / ds;
        const float a   = sane(c3*inv);
        const float bb  = sane(-(c1 + c2)*inv);
        const float cc  = sane(c0*inv);
        const float dd2 = sane(-(2.f*a*px + bb*py));
        const float ee  = sane(-(2.f*cc*py + bb*px));
        const float ff  = sane((a*px + bb*py)*px + cc*py*py);
        cPos[tid] = make_float2(px, py);
        nP[tid]   = make_float4(a, bb, cc, dd2);
        nQ[tid]   = make_float4(ee, ff, w, 0.f);
        cC[tid]   = make_float4(sane(c0), sane(c1), sane(c2), sane(c3));
    }
    __syncthreads();

    // ---- Phase B: eval_at_centers. k-slots paired (v_pk_fma_f32); per-n LDS
    // broadcast software-pipelined 2 deep: n+1's P/Q load issues before n's
    // exp chain, so the ds_read latency overlaps the FMA/exp work.
    v2f kxP[PPAD], kyP[PPAD], kx2P[PPAD], ky2P[PPAD], kxyP[PPAD], accP[PPAD];
    float kxS = 0.f, kyS = 0.f, kx2S = 0.f, ky2S = 0.f, kxyS = 0.f, accS = 0.f;
    #pragma unroll
    for (int p = 0; p < NPAIR; ++p) {
        float x0 = 0.f, y0 = 0.f, x1 = 0.f, y1 = 0.f;
        if (active) {
            const float2 p0 = cPos[kt + (2*p    )*KUSE];
            const float2 p1 = cPos[kt + (2*p + 1)*KUSE];
            x0 = p0.x; y0 = p0.y; x1 = p1.x; y1 = p1.y;
        }
        v2f kx; kx.x = x0; kx.y = x1;
        v2f ky; ky.x = y0; ky.y = y1;
        kxP[p] = kx; kyP[p] = ky;
        kx2P[p] = kx*kx; ky2P[p] = ky*ky; kxyP[p] = kx*ky;
        v2f z; z.x = 0.f; z.y = 0.f; accP[p] = z;
    }
    if constexpr (ODD) {
        if (active) { const float2 pz = cPos[kt + (KP-1)*KUSE]; kxS = pz.x; kyS = pz.y; }
        kx2S = kxS*kxS; ky2S = kyS*kyS; kxyS = kxS*kyS;
    }
    {
        const int n0 = g*CHUNK;
        const int n1 = (n0 + CHUNK < NCOMP) ? (n0 + CHUNK) : NCOMP;
        if (n0 < n1) {
            float4 P = nP[n0], Q = nQ[n0];
            #pragma unroll 2
            for (int n = n0; n < n1; ++n) {
                const int nn = (n + 1 < n1) ? n + 1 : n0;
                const float4 Pn = nP[nn];   // prefetch: issues before exp chain
                const float4 Qn = nQ[nn];
                v2f Pa; Pa.x = P.x; Pa.y = P.x;
                v2f Pb; Pb.x = P.y; Pb.y = P.y;
                v2f Pc; Pc.x = P.z; Pc.y = P.z;
                v2f Pd; Pd.x = P.w; Pd.y = P.w;
                v2f Qe; Qe.x = Q.x; Qe.y = Q.x;
                v2f Qf; Qf.x = Q.y; Qf.y = Q.y;
                v2f Qw; Qw.x = Q.z; Qw.y = Q.z;
                #pragma unroll
                for (int p = 0; p < NPAIR; ++p) {
                    const v2f md = __builtin_elementwise_fma(Pa, kx2P[p],
                                   __builtin_elementwise_fma(Pb, kxyP[p],
                                   __builtin_elementwise_fma(Pc, ky2P[p],
                                   __builtin_elementwise_fma(Pd, kxP[p],
                                   __builtin_elementwise_fma(Qe, kyP[p], Qf)))));
                    v2f ex; ex.x = EXP2F(md.x); ex.y = EXP2F(md.y);
                    accP[p] = __builtin_elementwise_fma(Qw, ex, accP[p]);
                }
                if constexpr (ODD) {
                    const float md = fmaf(P.x, kx2S,
                                     fmaf(P.y, kxyS,
                                     fmaf(P.z, ky2S,
                                     fmaf(P.w, kxS,
                                     fmaf(Q.x, kyS, Q.y)))));
                    accS = fmaf(Q.z, EXP2F(md), accS);
                }
                P = Pn; Q = Qn;
            }
        }
    }
    // Unpack pairs back to per-slot acc[]
    float acc[KP];
    #pragma unroll
    for (int p = 0; p < NPAIR; ++p) { acc[2*p] = accP[p].x; acc[2*p+1] = accP[p].y; }
    if constexpr (ODD) acc[KP-1] = accS;

    if (g > 0 && active) {
        #pragma unroll
        for (int j = 0; j < KP; ++j) accbuf[((g-1)*TPG + kt)*KP + j] = acc[j];
    }
    __syncthreads();

    const float bi = bias[lo];
    if (g == 0 && active) {
        #pragma unroll
        for (int j = 0; j < KP; ++j) {
            float s = acc[j];
            for (int gg = 1; gg < G; ++gg) s += accbuf[((gg-1)*TPG + kt)*KP + j];
            const float v  = s + bi;
            const float sc = fmaxf(v, 0.f) / (fabsf(v) + EPS_F);
            const int   k  = kt + j*KUSE;
            const float ww = sane(nQ[k].z * sc);
            w2s[k] = ww;
            a2s[k] = fabsf(ww);
        }
    }
    if constexpr (NCOMP4 > NCOMP) {
        if (tid >= NCOMP && tid < NCOMP4) a2s[tid] = -1.f;  // pad: never ranks
    }
    __syncthreads();

    // ---- Phase C: stable-descending rank (== jax.lax.top_k order), group-split
    int rank[KP];
    float myv[KP];
    #pragma unroll
    for (int j = 0; j < KP; ++j) rank[j] = 0;
    if (active) {
        #pragma unroll
        for (int j = 0; j < KP; ++j) myv[j] = a2s[kt + j*KUSE];
        const int q0 = g*CQ;
        const int q1 = (q0 + CQ < NQn) ? (q0 + CQ) : NQn;
        for (int q = q0; q < q1; ++q) {
            const float4 v4 = ((const float4*)a2s)[q];  // broadcast
            #pragma unroll
            for (int c = 0; c < 4; ++c) {
                const float vj = (c == 0) ? v4.x : (c == 1) ? v4.y : (c == 2) ? v4.z : v4.w;
                const int   jj = 4*q + c;
                #pragma unroll
                for (int j = 0; j < KP; ++j) {
                    const int myk = kt + j*KUSE;
                    rank[j] += (vj > myv[j] || (vj == myv[j] && jj < myk)) ? 1 : 0;
                }
            }
        }
        if (g > 0) {
            #pragma unroll
            for (int j = 0; j < KP; ++j) accbuf[((g-1)*TPG + kt)*KP + j] = (float)rank[j];
        }
    }
    __syncthreads();

    // ---- Phase D: g==0 finalizes ranks, writes selected comps + integrals
    if (g == 0 && active) {
        #pragma unroll
        for (int j = 0; j < KP; ++j) {
            int r = rank[j];
            for (int gg = 1; gg < G; ++gg) r += (int)accbuf[((gg-1)*TPG + kt)*KP + j];
            if (r < KOUT) {
                const int k = kt + j*KUSE;
                const float2 p = cPos[k];
                const float4 c = cC[k];
                const float ww = w2s[k];
                float* dst = out_sel + (size_t)((b*LO + lo)*KOUT + r)*7;
                dst[0] = ww; dst[1] = p.x; dst[2] = p.y;
                dst[3] = c.x; dst[4] = c.y; dst[5] = c.z; dst[6] = c.w;
                const float det = c.x*c.w - c.y*c.z;
                selint[r] = sane(fabsf(ww) * TWO_PI_F * sqrtf(fmaxf(det, EPS_F)));
            }
        }
    }
    __syncthreads();
    if (tid == 0) {
        float s = 0.f;
        for (int i = 0; i < KOUT; ++i) s += selint[i];
        out_tot[b*LO + lo] = s;
    }
}

// Final: batchnorm3 scale (mean over batch) -> integrate -> log_softmax -> f32
__global__ __launch_bounds__(64) void final_kernel(
    const float* __restrict__ sel3,   // (B,10,5,7)
    const float* __restrict__ tot3,   // (B,10)
    float* __restrict__ out)          // (B,10) f32
{
    const int b = blockIdx.x;
    const int tid = threadIdx.x;
    __shared__ float scale3[10], integ[10], red2[2];
    if (tid < 10) {
        float s = 0.f;
        for (int bb = 0; bb < BATCH; ++bb) s += tot3[bb*10 + tid];
        scale3[tid] = 1.f / (s / (float)BATCH + EPS_F);
    }
    __syncthreads();
    if (tid < 10) {
        float s = 0.f;
        const float* base = sel3 + (size_t)((b*10 + tid)*5)*7;
        for (int kk = 0; kk < 5; ++kk) {
            const float* c = base + kk*7;
            const float det = c[3]*c[6] - c[4]*c[5];
            s += c[0] * scale3[tid] * TWO_PI_F * sqrtf(fmaxf(det, EPS_F));
        }
        integ[tid] = sane(s);
    }
    __syncthreads();
    if (tid == 0) {
        float m = -1e30f;
        for (int l = 0; l < 10; ++l) m = fmaxf(m, integ[l]);
        float ss = 0.f;
        for (int l = 0; l < 10; ++l) ss += __expf(integ[l] - m);
        red2[0] = m; red2[1] = logf(ss);
    }
    __syncthreads();
    if (tid < 10) out[b*10 + tid] = integ[tid] - red2[0] - red2[1];
}

extern "C" void kernel_launch(void* const* d_in, const int* in_sizes, int n_in,
                              void* d_out, int out_size, void* d_ws, size_t ws_size,
                              hipStream_t stream)
{
    const float* in_x = (const float*)d_in[0];
    const float* k1   = (const float*)d_in[1];
    const float* k2   = (const float*)d_in[2];
    const float* k3   = (const float*)d_in[3];
    const float* b1   = (const float*)d_in[4];
    const float* b2   = (const float*)d_in[5];
    const float* b3   = (const float*)d_in[6];
    float* out = (float*)d_out;   // reference output dtype is float32

    float* ws = (float*)d_ws;
    float* sel1 = ws;                  // 32*5*25*7  = 28000 floats
    float* tot1 = ws + 28000;          // 160
    float* sel2 = ws + 28160;          // 32*6*12*7  = 16128
    float* tot2 = ws + 44288;          // 192
    float* sel3 = ws + 44480;          // 32*10*5*7  = 11200
    float* tot3 = ws + 55680;          // 320  (total ~224 KB)

    // Layer 1: 320 comps, keep 25.  KP=5 (64*5=320), TPG=64, G=16 -> NT=1024.
    layer_kernel<5, 1, 64, 5, 320, 25, 5, 64, 16, true><<<BATCH*5, 1024, 0, stream>>>(
        in_x, nullptr, nullptr, k1, b1, sel1, tot1);
    // Layer 2: 625 comps, keep 12.  KP=5 (125*5=625), TPG=128, G=8 -> NT=1024.
    layer_kernel<6, 5, 25, 5, 625, 12, 5, 128, 8, false><<<BATCH*6, 1024, 0, stream>>>(
        nullptr, sel1, tot1, k2, b2, sel2, tot2);
    // Layer 3: 360 comps, keep 5.   KP=6 (60*6=360), TPG=64, G=12 -> NT=768.
    layer_kernel<10, 6, 12, 5, 360, 5, 6, 64, 12, false><<<BATCH*10, 768, 0, stream>>>(
        nullptr, sel2, tot2, k3, b3, sel3, tot3);
    // Final: batchnorm + integrate + log_softmax.
    final_kernel<<<BATCH, 64, 0, stream>>>(sel3, tot3, out);
}